// Round 1
// baseline (4393.088 us; speedup 1.0000x reference)
//
#include <hip/hip_runtime.h>

#define H 150
#define RNUM 35
#define BNUM 5
#define IB 30
#define CHUNK 256

// ---------------- counting kernels ----------------

__global__ void k_count(const int* __restrict__ ei, const int* __restrict__ et,
                        int E_, int* __restrict__ cnt, int* __restrict__ relhist) {
    int e = blockIdx.x * blockDim.x + threadIdx.x;
    if (e >= E_) return;
    int d = ei[E_ + e];
    int r = et[e];
    atomicAdd(&cnt[d * RNUM + r], 1);
    atomicAdd(&relhist[r], 1);
}

__global__ void k_scan(const int* __restrict__ relhist, int* __restrict__ relbase,
                       int* __restrict__ chunk_rel, int* __restrict__ chunk_beg,
                       int* __restrict__ chunk_end, int* __restrict__ nch_out) {
    __shared__ int chunkbase[RNUM + 1];
    if (threadIdx.x == 0) {
        int base = 0, cb = 0;
        for (int r = 0; r < RNUM; ++r) {
            relbase[r] = base;
            chunkbase[r] = cb;
            base += relhist[r];
            cb += (relhist[r] + CHUNK - 1) / CHUNK;
        }
        relbase[RNUM] = base;
        chunkbase[RNUM] = cb;
        *nch_out = cb;
    }
    __syncthreads();
    int r = threadIdx.x;
    if (r < RNUM) {
        int nb = (relhist[r] + CHUNK - 1) / CHUNK;
        int rb = relbase[r];
        int cb = chunkbase[r];
        int re = rb + relhist[r];
        for (int c = 0; c < nb; ++c) {
            chunk_rel[cb + c] = r;
            chunk_beg[cb + c] = rb + c * CHUNK;
            int ev = rb + (c + 1) * CHUNK;
            chunk_end[cb + c] = ev < re ? ev : re;
        }
    }
}

__global__ void k_scatter(const int* __restrict__ ei, const int* __restrict__ et,
                          int E_, const int* __restrict__ relbase, int* __restrict__ relfill,
                          int* __restrict__ ssrc, int* __restrict__ sdst) {
    int e = blockIdx.x * blockDim.x + threadIdx.x;
    if (e >= E_) return;
    int r = et[e];
    int p = relbase[r] + atomicAdd(&relfill[r], 1);
    ssrc[p] = ei[e];
    sdst[p] = ei[E_ + e];
}

// transpose both weight tensors: wt[(r*B+b)][o][i] = w[(r*B+b)][i][o]
__global__ void k_transpose_w(const float* __restrict__ w1, const float* __restrict__ w2,
                              float* __restrict__ wt1, float* __restrict__ wt2) {
    const int tot = RNUM * BNUM * IB * IB;
    int idx = blockIdx.x * blockDim.x + threadIdx.x;
    if (idx >= 2 * tot) return;
    const float* w = (idx < tot) ? w1 : w2;
    float* wt = (idx < tot) ? wt1 : wt2;
    int k = (idx < tot) ? idx : idx - tot;
    int o = k % IB;
    int t2 = k / IB;
    int i = t2 % IB;
    int rb = t2 / IB;
    wt[(rb * IB + o) * IB + i] = w[k];
}

// ---------------- dense root transform: outb[n,o] = bias[o] + sum_h x[n,h]*root[h,o] ----------------
// grid = 3 col-tiles * 256 slots; each block caches a 150x50 root tile in LDS.

__global__ void k_root(const float* __restrict__ xin, const float* __restrict__ root,
                       const float* __restrict__ bias, float* __restrict__ outb, int N_) {
    __shared__ float rootS[150 * 50];
    __shared__ float xs[5 * 150];
    int ct = blockIdx.x >> 8;          // 0..2
    int slot = blockIdx.x & 255;
    int t = threadIdx.x;
    for (int li = t; li < 150 * 50; li += 256) {
        int h = li / 50, ol = li % 50;
        rootS[li] = root[h * 150 + ct * 50 + ol];
    }
    int ngroups = (N_ + 4) / 5;
    for (int g = slot; g < ngroups; g += 256) {
        __syncthreads();
        int base = g * 5 * 150;
        for (int li = t; li < 750; li += 256) {
            int gi = base + li;
            xs[li] = (gi < N_ * 150) ? xin[gi] : 0.f;
        }
        __syncthreads();
        if (t < 250) {
            int nl = t / 50, ol = t % 50;
            int ng = g * 5 + nl;
            if (ng < N_) {
                int o = ct * 50 + ol;
                float acc = bias[o];
                #pragma unroll 10
                for (int h = 0; h < 150; ++h)
                    acc = fmaf(xs[nl * 150 + h], rootS[h * 50 + ol], acc);
                outb[ng * 150 + o] = acc;
            }
        }
    }
}

// ---------------- per-edge block-diag transform + atomic scatter ----------------
// Edges sorted by relation; each block handles CHUNK edges of one relation.
// Wave = 1 edge/iteration; lane l<50: block b=l/10, outputs j..j+2 (j=3*(l%10)).

__global__ void k_edge(const int* __restrict__ ssrc, const int* __restrict__ sdst,
                       const int* __restrict__ cnt,
                       const int* __restrict__ chunk_rel, const int* __restrict__ chunk_beg,
                       const int* __restrict__ chunk_end, const int* __restrict__ nch,
                       const float* __restrict__ wt, const float* __restrict__ xin,
                       float* __restrict__ outb) {
    int g = blockIdx.x;
    if (g >= *nch) return;
    int r = chunk_rel[g];
    int t = threadIdx.x;
    int wv = t >> 6;
    int l = t & 63;
    bool active = (l < 50);
    int b = active ? (l / 10) : 0;
    int q = l % 10;
    int j = q * 3;

    // load this lane's 3 rows of Wt[r][b] into registers
    float w0[IB], w1r[IB], w2r[IB];
    const float* wbase = wt + ((r * BNUM + b) * IB) * IB;
    #pragma unroll
    for (int i = 0; i < IB; ++i) {
        w0[i]  = wbase[(j + 0) * IB + i];
        w1r[i] = wbase[(j + 1) * IB + i];
        w2r[i] = wbase[(j + 2) * IB + i];
    }

    int beg = chunk_beg[g], end = chunk_end[g];
    for (int e = beg + wv; e < end; e += 4) {
        int s = ssrc[e];
        int d = sdst[e];
        float inv = 1.0f / (float)cnt[d * RNUM + r];
        const float* xrow = xin + (size_t)s * H + b * IB;
        float a0 = 0.f, a1 = 0.f, a2 = 0.f;
        #pragma unroll
        for (int i = 0; i < IB; i += 2) {
            float2 xv = *reinterpret_cast<const float2*>(xrow + i);
            a0 = fmaf(w0[i],  xv.x, a0); a0 = fmaf(w0[i + 1],  xv.y, a0);
            a1 = fmaf(w1r[i], xv.x, a1); a1 = fmaf(w1r[i + 1], xv.y, a1);
            a2 = fmaf(w2r[i], xv.x, a2); a2 = fmaf(w2r[i + 1], xv.y, a2);
        }
        if (active) {
            float* orow = outb + (size_t)d * H + b * IB + j;
            atomicAdd(orow + 0, a0 * inv);
            atomicAdd(orow + 1, a1 * inv);
            atomicAdd(orow + 2, a2 * inv);
        }
    }
}

__global__ void k_relu(float* __restrict__ x, int n) {
    int i = blockIdx.x * blockDim.x + threadIdx.x;
    if (i < n) x[i] = fmaxf(x[i], 0.f);
}

// ---------------- launch ----------------

extern "C" void kernel_launch(void* const* d_in, const int* in_sizes, int n_in,
                              void* d_out, int out_size, void* d_ws, size_t ws_size,
                              hipStream_t stream) {
    const float* node_emb = (const float*)d_in[0];
    const float* w1 = (const float*)d_in[1];
    const float* root1 = (const float*)d_in[2];
    const float* b1 = (const float*)d_in[3];
    const float* w2 = (const float*)d_in[4];
    const float* root2 = (const float*)d_in[5];
    const float* b2 = (const float*)d_in[6];
    const int* edge_index = (const int*)d_in[7];
    const int* edge_type = (const int*)d_in[8];
    int N_ = in_sizes[0] / H;
    int E_ = in_sizes[8];
    float* out = (float*)d_out;

    int* ws = (int*)d_ws;
    size_t off = 0;
    int* cnt = ws;                 off += (size_t)N_ * RNUM;
    int* relhist = ws + off;       off += 64;
    int* relfill = ws + off;       off += 64;
    int* relbase = ws + off;       off += 64;
    int* nch = ws + off;           off += 16;
    size_t zero_units = off;
    int* chunk_rel = ws + off;     off += 2560;
    int* chunk_beg = ws + off;     off += 2560;
    int* chunk_end = ws + off;     off += 2560;
    int* ssrc = ws + off;          off += E_;
    int* sdst = ws + off;          off += E_;
    float* wt1 = (float*)(ws + off); off += RNUM * BNUM * IB * IB;
    float* wt2 = (float*)(ws + off); off += RNUM * BNUM * IB * IB;
    float* buf1 = (float*)(ws + off); off += (size_t)N_ * H;

    hipMemsetAsync(d_ws, 0, zero_units * 4, stream);

    k_count<<<(E_ + 255) / 256, 256, 0, stream>>>(edge_index, edge_type, E_, cnt, relhist);
    k_scan<<<1, 64, 0, stream>>>(relhist, relbase, chunk_rel, chunk_beg, chunk_end, nch);
    k_scatter<<<(E_ + 255) / 256, 256, 0, stream>>>(edge_index, edge_type, E_, relbase, relfill, ssrc, sdst);

    const int wtot = RNUM * BNUM * IB * IB;
    k_transpose_w<<<(2 * wtot + 255) / 256, 256, 0, stream>>>(w1, w2, wt1, wt2);

    int maxch = (E_ + CHUNK - 1) / CHUNK + RNUM;

    // layer 1
    k_root<<<768, 256, 0, stream>>>(node_emb, root1, b1, buf1, N_);
    k_edge<<<maxch, 256, 0, stream>>>(ssrc, sdst, cnt, chunk_rel, chunk_beg, chunk_end, nch,
                                      wt1, node_emb, buf1);
    k_relu<<<(N_ * H + 255) / 256, 256, 0, stream>>>(buf1, N_ * H);

    // layer 2
    k_root<<<768, 256, 0, stream>>>(buf1, root2, b2, out, N_);
    k_edge<<<maxch, 256, 0, stream>>>(ssrc, sdst, cnt, chunk_rel, chunk_beg, chunk_end, nch,
                                      wt2, buf1, out);
}

// Round 2
// 2293.434 us; speedup vs baseline: 1.9155x; 1.9155x over previous
//
#include <hip/hip_runtime.h>

#define H 150
#define RNUM 35
#define BNUM 5
#define IB 30
#define CHUNK 256

// ---------------- counting kernels (LDS-aggregated: avoid 35-address atomic storm) ----------------

__global__ void k_count(const int* __restrict__ ei, const int* __restrict__ et,
                        int E_, int* __restrict__ cnt, int* __restrict__ relhist) {
    __shared__ int lh[RNUM];
    for (int i = threadIdx.x; i < RNUM; i += blockDim.x) lh[i] = 0;
    __syncthreads();
    for (int e = blockIdx.x * blockDim.x + threadIdx.x; e < E_; e += gridDim.x * blockDim.x) {
        int d = ei[E_ + e];
        int r = et[e];
        atomicAdd(&cnt[d * RNUM + r], 1);   // scattered over 2.8 MB: fine
        atomicAdd(&lh[r], 1);               // LDS: fast
    }
    __syncthreads();
    for (int i = threadIdx.x; i < RNUM; i += blockDim.x)
        if (lh[i]) atomicAdd(&relhist[i], lh[i]);  // 512*35 total global atomics
}

__global__ void k_scan(const int* __restrict__ relhist, int* __restrict__ relbase,
                       int* __restrict__ chunk_rel, int* __restrict__ chunk_beg,
                       int* __restrict__ chunk_end, int* __restrict__ nch_out) {
    __shared__ int chunkbase[RNUM + 1];
    if (threadIdx.x == 0) {
        int base = 0, cb = 0;
        for (int r = 0; r < RNUM; ++r) {
            relbase[r] = base;
            chunkbase[r] = cb;
            base += relhist[r];
            cb += (relhist[r] + CHUNK - 1) / CHUNK;
        }
        relbase[RNUM] = base;
        chunkbase[RNUM] = cb;
        *nch_out = cb;
    }
    __syncthreads();
    int r = threadIdx.x;
    if (r < RNUM) {
        int nb = (relhist[r] + CHUNK - 1) / CHUNK;
        int rb = relbase[r];
        int cb = chunkbase[r];
        int re = rb + relhist[r];
        for (int c = 0; c < nb; ++c) {
            chunk_rel[cb + c] = r;
            chunk_beg[cb + c] = rb + c * CHUNK;
            int ev = rb + (c + 1) * CHUNK;
            chunk_end[cb + c] = ev < re ? ev : re;
        }
    }
}

// two-pass: per-block LDS count -> one reservation per (block,rel) -> rank via LDS atomics
__global__ void k_scatter(const int* __restrict__ ei, const int* __restrict__ et,
                          int E_, const int* __restrict__ relbase, int* __restrict__ relfill,
                          int* __restrict__ ssrc, int* __restrict__ sdst) {
    __shared__ int lh[RNUM];
    __shared__ int lbase[RNUM];
    for (int i = threadIdx.x; i < RNUM; i += blockDim.x) lh[i] = 0;
    __syncthreads();
    const int stride = gridDim.x * blockDim.x;
    for (int e = blockIdx.x * blockDim.x + threadIdx.x; e < E_; e += stride)
        atomicAdd(&lh[et[e]], 1);
    __syncthreads();
    for (int i = threadIdx.x; i < RNUM; i += blockDim.x) {
        int c = lh[i];
        lbase[i] = relbase[i] + (c ? atomicAdd(&relfill[i], c) : 0);
        lh[i] = 0;
    }
    __syncthreads();
    for (int e = blockIdx.x * blockDim.x + threadIdx.x; e < E_; e += stride) {
        int r = et[e];
        int rank = atomicAdd(&lh[r], 1);
        int p = lbase[r] + rank;
        ssrc[p] = ei[e];
        sdst[p] = ei[E_ + e];
    }
}

// transpose both weight tensors: wt[(r*B+b)][o][i] = w[(r*B+b)][i][o]
__global__ void k_transpose_w(const float* __restrict__ w1, const float* __restrict__ w2,
                              float* __restrict__ wt1, float* __restrict__ wt2) {
    const int tot = RNUM * BNUM * IB * IB;
    int idx = blockIdx.x * blockDim.x + threadIdx.x;
    if (idx >= 2 * tot) return;
    const float* w = (idx < tot) ? w1 : w2;
    float* wt = (idx < tot) ? wt1 : wt2;
    int k = (idx < tot) ? idx : idx - tot;
    int o = k % IB;
    int t2 = k / IB;
    int i = t2 % IB;
    int rb = t2 / IB;
    wt[(rb * IB + o) * IB + i] = w[k];
}

// ---------------- dense root transform: outb[n,o] = bias[o] + sum_h x[n,h]*root[h,o] ----------------

__global__ void k_root(const float* __restrict__ xin, const float* __restrict__ root,
                       const float* __restrict__ bias, float* __restrict__ outb, int N_) {
    __shared__ float rootS[150 * 50];
    __shared__ float xs[5 * 150];
    int ct = blockIdx.x >> 8;          // 0..2
    int slot = blockIdx.x & 255;
    int t = threadIdx.x;
    for (int li = t; li < 150 * 50; li += 256) {
        int h = li / 50, ol = li % 50;
        rootS[li] = root[h * 150 + ct * 50 + ol];
    }
    int ngroups = (N_ + 4) / 5;
    for (int g = slot; g < ngroups; g += 256) {
        __syncthreads();
        int base = g * 5 * 150;
        for (int li = t; li < 750; li += 256) {
            int gi = base + li;
            xs[li] = (gi < N_ * 150) ? xin[gi] : 0.f;
        }
        __syncthreads();
        if (t < 250) {
            int nl = t / 50, ol = t % 50;
            int ng = g * 5 + nl;
            if (ng < N_) {
                int o = ct * 50 + ol;
                float acc = bias[o];
                #pragma unroll 10
                for (int h = 0; h < 150; ++h)
                    acc = fmaf(xs[nl * 150 + h], rootS[h * 50 + ol], acc);
                outb[ng * 150 + o] = acc;
            }
        }
    }
}

// ---------------- per-edge block-diag transform + atomic scatter ----------------

__global__ void k_edge(const int* __restrict__ ssrc, const int* __restrict__ sdst,
                       const int* __restrict__ cnt,
                       const int* __restrict__ chunk_rel, const int* __restrict__ chunk_beg,
                       const int* __restrict__ chunk_end, const int* __restrict__ nch,
                       const float* __restrict__ wt, const float* __restrict__ xin,
                       float* __restrict__ outb) {
    int g = blockIdx.x;
    if (g >= *nch) return;
    int r = chunk_rel[g];
    int t = threadIdx.x;
    int wv = t >> 6;
    int l = t & 63;
    bool active = (l < 50);
    int b = active ? (l / 10) : 0;
    int q = l % 10;
    int j = q * 3;

    float w0[IB], w1r[IB], w2r[IB];
    const float* wbase = wt + ((r * BNUM + b) * IB) * IB;
    #pragma unroll
    for (int i = 0; i < IB; ++i) {
        w0[i]  = wbase[(j + 0) * IB + i];
        w1r[i] = wbase[(j + 1) * IB + i];
        w2r[i] = wbase[(j + 2) * IB + i];
    }

    int beg = chunk_beg[g], end = chunk_end[g];
    for (int e = beg + wv; e < end; e += 4) {
        int s = ssrc[e];
        int d = sdst[e];
        float inv = 1.0f / (float)cnt[d * RNUM + r];
        const float* xrow = xin + (size_t)s * H + b * IB;
        float a0 = 0.f, a1 = 0.f, a2 = 0.f;
        #pragma unroll
        for (int i = 0; i < IB; i += 2) {
            float2 xv = *reinterpret_cast<const float2*>(xrow + i);
            a0 = fmaf(w0[i],  xv.x, a0); a0 = fmaf(w0[i + 1],  xv.y, a0);
            a1 = fmaf(w1r[i], xv.x, a1); a1 = fmaf(w1r[i + 1], xv.y, a1);
            a2 = fmaf(w2r[i], xv.x, a2); a2 = fmaf(w2r[i + 1], xv.y, a2);
        }
        if (active) {
            float* orow = outb + (size_t)d * H + b * IB + j;
            atomicAdd(orow + 0, a0 * inv);
            atomicAdd(orow + 1, a1 * inv);
            atomicAdd(orow + 2, a2 * inv);
        }
    }
}

__global__ void k_relu(float* __restrict__ x, int n) {
    int i = blockIdx.x * blockDim.x + threadIdx.x;
    if (i < n) x[i] = fmaxf(x[i], 0.f);
}

// ---------------- launch ----------------

extern "C" void kernel_launch(void* const* d_in, const int* in_sizes, int n_in,
                              void* d_out, int out_size, void* d_ws, size_t ws_size,
                              hipStream_t stream) {
    const float* node_emb = (const float*)d_in[0];
    const float* w1 = (const float*)d_in[1];
    const float* root1 = (const float*)d_in[2];
    const float* b1 = (const float*)d_in[3];
    const float* w2 = (const float*)d_in[4];
    const float* root2 = (const float*)d_in[5];
    const float* b2 = (const float*)d_in[6];
    const int* edge_index = (const int*)d_in[7];
    const int* edge_type = (const int*)d_in[8];
    int N_ = in_sizes[0] / H;
    int E_ = in_sizes[8];
    float* out = (float*)d_out;

    int* ws = (int*)d_ws;
    size_t off = 0;
    int* cnt = ws;                 off += (size_t)N_ * RNUM;
    int* relhist = ws + off;       off += 64;
    int* relfill = ws + off;       off += 64;
    int* relbase = ws + off;       off += 64;
    int* nch = ws + off;           off += 16;
    size_t zero_units = off;
    int* chunk_rel = ws + off;     off += 2560;
    int* chunk_beg = ws + off;     off += 2560;
    int* chunk_end = ws + off;     off += 2560;
    int* ssrc = ws + off;          off += E_;
    int* sdst = ws + off;          off += E_;
    float* wt1 = (float*)(ws + off); off += RNUM * BNUM * IB * IB;
    float* wt2 = (float*)(ws + off); off += RNUM * BNUM * IB * IB;
    float* buf1 = (float*)(ws + off); off += (size_t)N_ * H;

    hipMemsetAsync(d_ws, 0, zero_units * 4, stream);

    k_count<<<512, 256, 0, stream>>>(edge_index, edge_type, E_, cnt, relhist);
    k_scan<<<1, 64, 0, stream>>>(relhist, relbase, chunk_rel, chunk_beg, chunk_end, nch);
    k_scatter<<<512, 256, 0, stream>>>(edge_index, edge_type, E_, relbase, relfill, ssrc, sdst);

    const int wtot = RNUM * BNUM * IB * IB;
    k_transpose_w<<<(2 * wtot + 255) / 256, 256, 0, stream>>>(w1, w2, wt1, wt2);

    int maxch = (E_ + CHUNK - 1) / CHUNK + RNUM;

    // layer 1
    k_root<<<768, 256, 0, stream>>>(node_emb, root1, b1, buf1, N_);
    k_edge<<<maxch, 256, 0, stream>>>(ssrc, sdst, cnt, chunk_rel, chunk_beg, chunk_end, nch,
                                      wt1, node_emb, buf1);
    k_relu<<<(N_ * H + 255) / 256, 256, 0, stream>>>(buf1, N_ * H);

    // layer 2
    k_root<<<768, 256, 0, stream>>>(buf1, root2, b2, out, N_);
    k_edge<<<maxch, 256, 0, stream>>>(ssrc, sdst, cnt, chunk_rel, chunk_beg, chunk_end, nch,
                                      wt2, buf1, out);
}

// Round 3
// 1428.338 us; speedup vs baseline: 3.0757x; 1.6057x over previous
//
#include <hip/hip_runtime.h>

#define H 150
#define RNUM 35
#define BNUM 5
#define IB 30

// =============== preprocessing ===============

// count edges per (dst, rel) cell
__global__ void k_count(const int* __restrict__ ei, const int* __restrict__ et,
                        int E_, int* __restrict__ cnt) {
    for (int e = blockIdx.x * blockDim.x + threadIdx.x; e < E_; e += gridDim.x * blockDim.x) {
        int d = ei[E_ + e];
        int r = et[e];
        atomicAdd(&cnt[d * RNUM + r], 1);   // scattered over 2.8 MB: fine
    }
}

// Scan machinery: block covers 512 dsts (256 threads x 2 dsts each).
#define SPT 2
#define SCAN_BLOCK 256
#define SCAN_SPAN (SPT * SCAN_BLOCK)

// pass A: per-block totals of (active segments, edges)
__global__ void k_scanA(const int* __restrict__ cnt, int N_,
                        int* __restrict__ blkN, int* __restrict__ blkD) {
    __shared__ int sn[SCAN_BLOCK], sd[SCAN_BLOCK];
    int t = threadIdx.x;
    int base = blockIdx.x * SCAN_SPAN + t * SPT;
    int tn = 0, td = 0;
    for (int k = 0; k < SPT; ++k) {
        int d = base + k;
        if (d < N_) {
            for (int r = 0; r < RNUM; ++r) {
                int c = cnt[d * RNUM + r];
                if (c) { tn++; td += c; }
            }
        }
    }
    sn[t] = tn; sd[t] = td;
    __syncthreads();
    if (t == 0) {
        int an = 0, ad = 0;
        for (int i = 0; i < SCAN_BLOCK; ++i) { an += sn[i]; ad += sd[i]; }
        blkN[blockIdx.x] = an; blkD[blockIdx.x] = ad;
    }
}

// pass B: exclusive scan of block totals (tiny)
__global__ void k_scanB(const int* __restrict__ blkN, const int* __restrict__ blkD,
                        int* __restrict__ blkBN, int* __restrict__ blkBD, int nblk) {
    if (threadIdx.x == 0 && blockIdx.x == 0) {
        int an = 0, ad = 0;
        for (int i = 0; i < nblk; ++i) {
            blkBN[i] = an; blkBD[i] = ad;
            an += blkN[i]; ad += blkD[i];
        }
    }
}

// pass C: write dstbase[d], and per-cell segoff (edge offset) / segidx (compact dst-major segment idx)
__global__ void k_scanC(const int* __restrict__ cnt, int N_,
                        const int* __restrict__ blkBN, const int* __restrict__ blkBD,
                        int* __restrict__ dstbase, int* __restrict__ segoff,
                        int* __restrict__ segidx) {
    __shared__ int sn[SCAN_BLOCK], sd[SCAN_BLOCK];
    int t = threadIdx.x;
    int base = blockIdx.x * SCAN_SPAN + t * SPT;
    int tn = 0, td = 0;
    for (int k = 0; k < SPT; ++k) {
        int d = base + k;
        if (d < N_) {
            for (int r = 0; r < RNUM; ++r) {
                int c = cnt[d * RNUM + r];
                if (c) { tn++; td += c; }
            }
        }
    }
    sn[t] = tn; sd[t] = td;
    __syncthreads();
    if (t == 0) {
        int an = blkBN[blockIdx.x], ad = blkBD[blockIdx.x];
        for (int i = 0; i < SCAN_BLOCK; ++i) {
            int a = sn[i], b = sd[i];
            sn[i] = an; sd[i] = ad;
            an += a; ad += b;
        }
    }
    __syncthreads();
    int sb = sn[t], eb = sd[t];
    for (int k = 0; k < SPT; ++k) {
        int d = base + k;
        if (d < N_) {
            dstbase[d] = sb;
            for (int r = 0; r < RNUM; ++r) {
                int cell = d * RNUM + r;
                int c = cnt[cell];
                segoff[cell] = eb;
                if (c) { segidx[cell] = sb; sb++; eb += c; }
            }
            if (d == N_ - 1) dstbase[N_] = sb;
        }
    }
}

// scatter src ids into segment-sorted order; advances segoff[cell] by cnt
// (k_seg recovers the base as segoff[cell] - cnt[cell])
__global__ void k_scatter2(const int* __restrict__ ei, const int* __restrict__ et,
                           int E_, int* __restrict__ segoff, int* __restrict__ ssrc2) {
    int e = blockIdx.x * blockDim.x + threadIdx.x;
    if (e >= E_) return;
    int r = et[e];
    int d = ei[E_ + e];
    int pos = atomicAdd(&segoff[d * RNUM + r], 1);
    ssrc2[pos] = ei[e];
}

// transpose both weight tensors: wt[(r*B+b)][o][i] = w[(r*B+b)][i][o]
__global__ void k_transpose_w(const float* __restrict__ w1, const float* __restrict__ w2,
                              float* __restrict__ wt1, float* __restrict__ wt2) {
    const int tot = RNUM * BNUM * IB * IB;
    int idx = blockIdx.x * blockDim.x + threadIdx.x;
    if (idx >= 2 * tot) return;
    const float* w = (idx < tot) ? w1 : w2;
    float* wt = (idx < tot) ? wt1 : wt2;
    int k = (idx < tot) ? idx : idx - tot;
    int o = k % IB;
    int t2 = k / IB;
    int i = t2 % IB;
    int rb = t2 / IB;
    wt[(rb * IB + o) * IB + i] = w[k];
}

// =============== dense root transform ===============
// outb[n,o] = bias[o] + sum_h x[n,h]*root[h,o]

__global__ void k_root(const float* __restrict__ xin, const float* __restrict__ root,
                       const float* __restrict__ bias, float* __restrict__ outb, int N_) {
    __shared__ float rootS[150 * 50];
    __shared__ float xs[5 * 150];
    int ct = blockIdx.x >> 8;          // 0..2
    int slot = blockIdx.x & 255;
    int t = threadIdx.x;
    for (int li = t; li < 150 * 50; li += 256) {
        int h = li / 50, ol = li % 50;
        rootS[li] = root[h * 150 + ct * 50 + ol];
    }
    int ngroups = (N_ + 4) / 5;
    for (int g = slot; g < ngroups; g += 256) {
        __syncthreads();
        int base = g * 5 * 150;
        for (int li = t; li < 750; li += 256) {
            int gi = base + li;
            xs[li] = (gi < N_ * 150) ? xin[gi] : 0.f;
        }
        __syncthreads();
        if (t < 250) {
            int nl = t / 50, ol = t % 50;
            int ng = g * 5 + nl;
            if (ng < N_) {
                int o = ct * 50 + ol;
                float acc = bias[o];
                #pragma unroll 10
                for (int h = 0; h < 150; ++h)
                    acc = fmaf(xs[nl * 150 + h], rootS[h * 50 + ol], acc);
                outb[ng * 150 + o] = acc;
            }
        }
    }
}

// =============== per-segment transform (atomic-free) ===============
// One wave per active (dst, rel) cell: sum src rows, mean, apply W_r^T (regs),
// write transformed row to tseg[segidx - segBase].  grid = (dst chunks, RNUM).

#define DCHUNK 64

__global__ void k_seg(const int* __restrict__ ssrc2, const int* __restrict__ cnt,
                      const int* __restrict__ segoff, const int* __restrict__ segidx,
                      const int* __restrict__ dstbase,
                      const float* __restrict__ wt, const float* __restrict__ xin,
                      float* __restrict__ tseg, int s0, int s1) {
    int r = blockIdx.y;
    int t = threadIdx.x;
    int wv = t >> 6;
    int l = t & 63;
    bool active = (l < 50);
    int b = active ? (l / 10) : 0;
    int j = (l % 10) * 3;

    // register-resident rows j..j+2 of W_r^T for block b
    float w0[IB], w1r[IB], w2r[IB];
    const float* wbase = wt + ((r * BNUM + b) * IB) * IB;
    #pragma unroll
    for (int i = 0; i < IB; ++i) {
        w0[i]  = wbase[(j + 0) * IB + i];
        w1r[i] = wbase[(j + 1) * IB + i];
        w2r[i] = wbase[(j + 2) * IB + i];
    }

    __shared__ float xsum[4][152];
    int segBase = dstbase[s0];
    int dstart = s0 + blockIdx.x * DCHUNK;
    int dend = dstart + DCHUNK; if (dend > s1) dend = s1;

    for (int d = dstart + wv; d < dend; d += 4) {
        int cell = d * RNUM + r;
        int c = cnt[cell];
        if (!c) continue;
        int eo = segoff[cell] - c;   // scatter advanced segoff by c
        float a0 = 0.f, a1 = 0.f, a2 = 0.f;
        for (int k = 0; k < c; ++k) {
            int s = ssrc2[eo + k];
            const float* xr = xin + (size_t)s * H + b * IB + j;
            a0 += xr[0]; a1 += xr[1]; a2 += xr[2];
        }
        float inv = 1.0f / (float)c;
        if (active) {
            xsum[wv][b * IB + j]     = a0 * inv;
            xsum[wv][b * IB + j + 1] = a1 * inv;
            xsum[wv][b * IB + j + 2] = a2 * inv;
        }
        asm volatile("s_waitcnt lgkmcnt(0)" ::: "memory");
        float o0 = 0.f, o1 = 0.f, o2 = 0.f;
        const float* xs = &xsum[wv][b * IB];
        #pragma unroll
        for (int i = 0; i < IB; ++i) {
            float xv = xs[i];
            o0 = fmaf(w0[i],  xv, o0);
            o1 = fmaf(w1r[i], xv, o1);
            o2 = fmaf(w2r[i], xv, o2);
        }
        asm volatile("s_waitcnt lgkmcnt(0)" ::: "memory");
        if (active) {
            int row = segidx[cell] - segBase;
            float* orow = tseg + (size_t)row * H + b * IB + j;
            orow[0] = o0; orow[1] = o1; orow[2] = o2;
        }
    }
}

// =============== per-dst aggregation: out[d] += sum of its (contiguous) tseg rows ===============

#define AGG_D 16

__global__ void k_aggadd(const float* __restrict__ tseg, const int* __restrict__ dstbase,
                         float* __restrict__ buf, int relu, int s0, int s1) {
    int t = threadIdx.x;
    int segBase = dstbase[s0];
    int d0 = s0 + blockIdx.x * AGG_D;
    for (int dd = 0; dd < AGG_D; ++dd) {
        int d = d0 + dd;
        if (d >= s1) break;
        int a = dstbase[d], bnd = dstbase[d + 1];
        if (t < H) {
            float acc = buf[(size_t)d * H + t];
            for (int s = a; s < bnd; ++s)
                acc += tseg[(size_t)(s - segBase) * H + t];
            if (relu) acc = fmaxf(acc, 0.f);
            buf[(size_t)d * H + t] = acc;
        }
    }
}

// =============== launch ===============

extern "C" void kernel_launch(void* const* d_in, const int* in_sizes, int n_in,
                              void* d_out, int out_size, void* d_ws, size_t ws_size,
                              hipStream_t stream) {
    const float* node_emb = (const float*)d_in[0];
    const float* w1 = (const float*)d_in[1];
    const float* root1 = (const float*)d_in[2];
    const float* b1 = (const float*)d_in[3];
    const float* w2 = (const float*)d_in[4];
    const float* root2 = (const float*)d_in[5];
    const float* b2 = (const float*)d_in[6];
    const int* edge_index = (const int*)d_in[7];
    const int* edge_type = (const int*)d_in[8];
    int N_ = in_sizes[0] / H;
    int E_ = in_sizes[8];
    float* out = (float*)d_out;

    const int Ncells = N_ * RNUM;
    const int wtot = RNUM * BNUM * IB * IB;

    int* ws = (int*)d_ws;
    size_t off = 0;
    int* cnt     = ws + off; off += Ncells;      // zeroed each call
    int* blkN    = ws + off; off += 64;
    int* blkD    = ws + off; off += 64;
    int* blkBN   = ws + off; off += 64;
    int* blkBD   = ws + off; off += 64;
    int* dstbase = ws + off; off += N_ + 2;
    int* segoff  = ws + off; off += Ncells;
    int* segidx  = ws + off; off += Ncells;
    int* ssrc2   = ws + off; off += E_;
    float* wt1   = (float*)(ws + off); off += wtot;
    float* wt2   = (float*)(ws + off); off += wtot;
    float* buf1  = (float*)(ws + off); off += (size_t)N_ * H;
    float* tseg  = (float*)(ws + off);
    size_t tsegOffB = off * 4;

    // adaptive striping: per-dst worst case RNUM rows of H floats
    size_t availB = (ws_size > tsegOffB) ? (ws_size - tsegOffB) : 0;
    long long dps_ll = (long long)(availB / ((size_t)RNUM * H * 4));
    int dps = (dps_ll > N_) ? N_ : (int)dps_ll;
    if (dps < 1) dps = 1;
    int nstripe = (N_ + dps - 1) / dps;

    hipMemsetAsync(cnt, 0, (size_t)Ncells * 4, stream);

    k_count<<<512, 256, 0, stream>>>(edge_index, edge_type, E_, cnt);

    int nscan = (N_ + SCAN_SPAN - 1) / SCAN_SPAN;
    k_scanA<<<nscan, SCAN_BLOCK, 0, stream>>>(cnt, N_, blkN, blkD);
    k_scanB<<<1, 64, 0, stream>>>(blkN, blkD, blkBN, blkBD, nscan);
    k_scanC<<<nscan, SCAN_BLOCK, 0, stream>>>(cnt, N_, blkBN, blkBD, dstbase, segoff, segidx);
    k_scatter2<<<(E_ + 255) / 256, 256, 0, stream>>>(edge_index, edge_type, E_, segoff, ssrc2);
    k_transpose_w<<<(2 * wtot + 255) / 256, 256, 0, stream>>>(w1, w2, wt1, wt2);

    // ---- layer 1 ----
    k_root<<<768, 256, 0, stream>>>(node_emb, root1, b1, buf1, N_);
    for (int st = 0; st < nstripe; ++st) {
        int s0 = st * dps;
        int s1 = s0 + dps; if (s1 > N_) s1 = N_;
        dim3 grid((s1 - s0 + DCHUNK - 1) / DCHUNK, RNUM);
        k_seg<<<grid, 256, 0, stream>>>(ssrc2, cnt, segoff, segidx, dstbase,
                                        wt1, node_emb, tseg, s0, s1);
        k_aggadd<<<(s1 - s0 + AGG_D - 1) / AGG_D, 192, 0, stream>>>(tseg, dstbase, buf1, 1, s0, s1);
    }

    // ---- layer 2 ----
    k_root<<<768, 256, 0, stream>>>(buf1, root2, b2, out, N_);
    for (int st = 0; st < nstripe; ++st) {
        int s0 = st * dps;
        int s1 = s0 + dps; if (s1 > N_) s1 = N_;
        dim3 grid((s1 - s0 + DCHUNK - 1) / DCHUNK, RNUM);
        k_seg<<<grid, 256, 0, stream>>>(ssrc2, cnt, segoff, segidx, dstbase,
                                        wt2, buf1, tseg, s0, s1);
        k_aggadd<<<(s1 - s0 + AGG_D - 1) / AGG_D, 192, 0, stream>>>(tseg, dstbase, out, 0, s0, s1);
    }
}

// Round 4
// 872.835 us; speedup vs baseline: 5.0331x; 1.6364x over previous
//
#include <hip/hip_runtime.h>
#include <hip/hip_fp16.h>

#define H 150
#define RNUM 35
#define BNUM 5
#define IB 30

typedef unsigned short ushort_t;
using bf16x8 = __attribute__((ext_vector_type(8))) short;
using f32x4  = __attribute__((ext_vector_type(4))) float;

__device__ __forceinline__ ushort_t f2bf(float x) {
    union { float f; unsigned u; } v; v.f = x;
    unsigned u = v.u;
    return (ushort_t)((u + 0x7FFF + ((u >> 16) & 1)) >> 16);
}

// =============== preprocessing ===============

__global__ void k_count(const int* __restrict__ ei, const int* __restrict__ et,
                        int E_, int* __restrict__ cnt) {
    for (int e = blockIdx.x * blockDim.x + threadIdx.x; e < E_; e += gridDim.x * blockDim.x) {
        int d = ei[E_ + e];
        int r = et[e];
        atomicAdd(&cnt[d * RNUM + r], 1);
    }
}

#define SPT 2
#define SCAN_BLOCK 256
#define SCAN_SPAN (SPT * SCAN_BLOCK)

__global__ void k_scanA(const int* __restrict__ cnt, int N_,
                        int* __restrict__ blkN, int* __restrict__ blkD) {
    __shared__ int sn[SCAN_BLOCK], sd[SCAN_BLOCK];
    int t = threadIdx.x;
    int base = blockIdx.x * SCAN_SPAN + t * SPT;
    int tn = 0, td = 0;
    for (int k = 0; k < SPT; ++k) {
        int d = base + k;
        if (d < N_) {
            for (int r = 0; r < RNUM; ++r) {
                int c = cnt[d * RNUM + r];
                if (c) { tn++; td += c; }
            }
        }
    }
    sn[t] = tn; sd[t] = td;
    __syncthreads();
    if (t == 0) {
        int an = 0, ad = 0;
        for (int i = 0; i < SCAN_BLOCK; ++i) { an += sn[i]; ad += sd[i]; }
        blkN[blockIdx.x] = an; blkD[blockIdx.x] = ad;
    }
}

__global__ void k_scanB(const int* __restrict__ blkN, const int* __restrict__ blkD,
                        int* __restrict__ blkBN, int* __restrict__ blkBD, int nblk) {
    if (threadIdx.x == 0 && blockIdx.x == 0) {
        int an = 0, ad = 0;
        for (int i = 0; i < nblk; ++i) {
            blkBN[i] = an; blkBD[i] = ad;
            an += blkN[i]; ad += blkD[i];
        }
    }
}

__global__ void k_scanC(const int* __restrict__ cnt, int N_,
                        const int* __restrict__ blkBN, const int* __restrict__ blkBD,
                        int* __restrict__ dstbase, int* __restrict__ segoff,
                        int* __restrict__ segidx) {
    __shared__ int sn[SCAN_BLOCK], sd[SCAN_BLOCK];
    int t = threadIdx.x;
    int base = blockIdx.x * SCAN_SPAN + t * SPT;
    int tn = 0, td = 0;
    for (int k = 0; k < SPT; ++k) {
        int d = base + k;
        if (d < N_) {
            for (int r = 0; r < RNUM; ++r) {
                int c = cnt[d * RNUM + r];
                if (c) { tn++; td += c; }
            }
        }
    }
    sn[t] = tn; sd[t] = td;
    __syncthreads();
    if (t == 0) {
        int an = blkBN[blockIdx.x], ad = blkBD[blockIdx.x];
        for (int i = 0; i < SCAN_BLOCK; ++i) {
            int a = sn[i], b = sd[i];
            sn[i] = an; sd[i] = ad;
            an += a; ad += b;
        }
    }
    __syncthreads();
    int sb = sn[t], eb = sd[t];
    for (int k = 0; k < SPT; ++k) {
        int d = base + k;
        if (d < N_) {
            dstbase[d] = sb;
            for (int r = 0; r < RNUM; ++r) {
                int cell = d * RNUM + r;
                int c = cnt[cell];
                segoff[cell] = eb;
                if (c) { segidx[cell] = sb; sb++; eb += c; }
            }
            if (d == N_ - 1) dstbase[N_] = sb;
        }
    }
}

__global__ void k_scatter2(const int* __restrict__ ei, const int* __restrict__ et,
                           int E_, int* __restrict__ segoff, int* __restrict__ ssrc2) {
    int e = blockIdx.x * blockDim.x + threadIdx.x;
    if (e >= E_) return;
    int r = et[e];
    int d = ei[E_ + e];
    int pos = atomicAdd(&segoff[d * RNUM + r], 1);
    ssrc2[pos] = ei[e];
}

// relation-major active-segment lists
__global__ void k_relcnt(const int* __restrict__ cnt, int Ncells, int* __restrict__ relhist2) {
    __shared__ int lh[RNUM];
    for (int i = threadIdx.x; i < RNUM; i += blockDim.x) lh[i] = 0;
    __syncthreads();
    for (int cell = blockIdx.x * blockDim.x + threadIdx.x; cell < Ncells;
         cell += gridDim.x * blockDim.x)
        if (cnt[cell]) atomicAdd(&lh[cell % RNUM], 1);
    __syncthreads();
    for (int i = threadIdx.x; i < RNUM; i += blockDim.x)
        if (lh[i]) atomicAdd(&relhist2[i], lh[i]);
}

__global__ void k_relbase(const int* __restrict__ relhist2, int* __restrict__ relbase2) {
    if (threadIdx.x == 0 && blockIdx.x == 0) {
        int a = 0;
        for (int r = 0; r < RNUM; ++r) { relbase2[r] = a; a += relhist2[r]; }
        relbase2[RNUM] = a;
    }
}

__global__ void k_relassign(const int* __restrict__ cnt, const int* __restrict__ segoff,
                            const int* __restrict__ segidx, int Ncells,
                            const int* __restrict__ relbase2, int* __restrict__ relfill2,
                            int4* __restrict__ rec) {
    __shared__ int lh[RNUM];
    __shared__ int lbase[RNUM];
    for (int i = threadIdx.x; i < RNUM; i += blockDim.x) lh[i] = 0;
    __syncthreads();
    const int stride = gridDim.x * blockDim.x;
    for (int cell = blockIdx.x * blockDim.x + threadIdx.x; cell < Ncells; cell += stride)
        if (cnt[cell]) atomicAdd(&lh[cell % RNUM], 1);
    __syncthreads();
    for (int i = threadIdx.x; i < RNUM; i += blockDim.x) {
        int c = lh[i];
        lbase[i] = relbase2[i] + (c ? atomicAdd(&relfill2[i], c) : 0);
        lh[i] = 0;
    }
    __syncthreads();
    for (int cell = blockIdx.x * blockDim.x + threadIdx.x; cell < Ncells; cell += stride) {
        int c = cnt[cell];
        if (c) {
            int r = cell % RNUM;
            int pos = lbase[r] + atomicAdd(&lh[r], 1);
            rec[pos] = make_int4(segidx[cell], segoff[cell] - c, c, 0);
        }
    }
}

__global__ void k_transpose_w(const float* __restrict__ w1, const float* __restrict__ w2,
                              float* __restrict__ wt1, float* __restrict__ wt2) {
    const int tot = RNUM * BNUM * IB * IB;
    int idx = blockIdx.x * blockDim.x + threadIdx.x;
    if (idx >= 2 * tot) return;
    const float* w = (idx < tot) ? w1 : w2;
    float* wt = (idx < tot) ? wt1 : wt2;
    int k = (idx < tot) ? idx : idx - tot;
    int o = k % IB;
    int t2 = k / IB;
    int i = t2 % IB;
    int rb = t2 / IB;
    wt[(rb * IB + o) * IB + i] = w[k];
}

// =============== bf16 conversions for MFMA root ===============

__global__ void k_convA(const float* __restrict__ x, ushort_t* __restrict__ Abf, int N_) {
    int i = blockIdx.x * blockDim.x + threadIdx.x;
    if (i >= N_ * 160) return;
    int n = i / 160, c = i - n * 160;
    Abf[i] = (c < H) ? f2bf(x[n * H + c]) : 0;
}

__global__ void k_convB(const float* __restrict__ r1, const float* __restrict__ r2,
                        ushort_t* __restrict__ B1, ushort_t* __restrict__ B2) {
    int i = blockIdx.x * blockDim.x + threadIdx.x;
    if (i >= 2 * 160 * 160) return;
    const float* src = (i < 160 * 160) ? r1 : r2;
    ushort_t* dst = (i < 160 * 160) ? B1 : B2;
    int k = (i < 160 * 160) ? i : i - 160 * 160;
    int row = k / 160, col = k - row * 160;
    dst[k] = (row < H && col < H) ? f2bf(src[row * H + col]) : 0;
}

// =============== root transform via MFMA bf16: C = A(20000x160) * B(160x160) + bias ===============

__global__ __launch_bounds__(256) void k_rootmm(const ushort_t* __restrict__ Abf,
                                                const ushort_t* __restrict__ Bbf,
                                                const float* __restrict__ bias,
                                                float* __restrict__ Cout, int N_) {
    int nt = blockIdx.y;                 // n-tile 0..9
    int wv = threadIdx.x >> 6, l = threadIdx.x & 63;
    int lr = l & 15, lk = l >> 4;
    // B-frags register-cached: B[(ks*32 + lk*8 + j)][nt*16 + lr]
    bf16x8 bfr[5];
    #pragma unroll
    for (int ks = 0; ks < 5; ++ks) {
        #pragma unroll
        for (int j = 0; j < 8; ++j)
            bfr[ks][j] = (short)Bbf[(ks * 32 + lk * 8 + j) * 160 + nt * 16 + lr];
    }
    int mtiles = N_ / 16;
    int col = nt * 16 + lr;
    float bv = (col < H) ? bias[col] : 0.f;
    for (int mt = blockIdx.x * 4 + wv; mt < mtiles; mt += gridDim.x * 4) {
        f32x4 acc = {0.f, 0.f, 0.f, 0.f};
        const ushort_t* arow = Abf + (size_t)(mt * 16 + lr) * 160 + lk * 8;
        #pragma unroll
        for (int ks = 0; ks < 5; ++ks) {
            bf16x8 af = *reinterpret_cast<const bf16x8*>(arow + ks * 32);
            acc = __builtin_amdgcn_mfma_f32_16x16x32_bf16(af, bfr[ks], acc, 0, 0, 0);
        }
        if (col < H) {
            #pragma unroll
            for (int reg = 0; reg < 4; ++reg)
                Cout[(size_t)(mt * 16 + lk * 4 + reg) * H + col] = acc[reg] + bv;
        }
    }
}

// =============== per-segment transform: rel-major records, W in regs, fp16 tseg ===============

__global__ __launch_bounds__(256, 3)
void k_seg(const int4* __restrict__ rec, const int* __restrict__ relbase2,
           const int* __restrict__ dstbase, const int* __restrict__ ssrc2,
           const float* __restrict__ wt, const float* __restrict__ xin,
           __half* __restrict__ tseg, int s0, int s1) {
    int r = blockIdx.y;
    int base = relbase2[r];
    int nseg = relbase2[r + 1] - base;
    int rowLo = dstbase[s0], rowHi = dstbase[s1];
    int t = threadIdx.x, wv = t >> 6, l = t & 63;
    bool active = (l < 50);
    int b = active ? (l / 10) : 0;
    int j = (l % 10) * 3;

    float w0[IB], w1r[IB], w2r[IB];
    const float* wbase = wt + ((r * BNUM + b) * IB) * IB;
    #pragma unroll
    for (int i = 0; i < IB; ++i) {
        w0[i]  = wbase[(j + 0) * IB + i];
        w1r[i] = wbase[(j + 1) * IB + i];
        w2r[i] = wbase[(j + 2) * IB + i];
    }

    __shared__ float xsum[4][BNUM][36];   // 36-stride: bank-staggered, 16B-aligned rows

    for (int i = blockIdx.x * 4 + wv; i < nseg; i += gridDim.x * 4) {
        int4 rc = rec[base + i];
        int row = rc.x;
        if (row < rowLo || row >= rowHi) continue;
        int eo = rc.y, c = rc.z;
        float a0 = 0.f, a1 = 0.f, a2 = 0.f;
        for (int k = 0; k < c; ++k) {
            int s = ssrc2[eo + k];
            const float* xr = xin + (size_t)s * H + b * IB + j;
            float2 xv = *reinterpret_cast<const float2*>(xr);
            a0 += xv.x; a1 += xv.y; a2 += xr[2];
        }
        float inv = 1.0f / (float)c;
        if (active) {
            xsum[wv][b][j]     = a0 * inv;
            xsum[wv][b][j + 1] = a1 * inv;
            xsum[wv][b][j + 2] = a2 * inv;
        }
        asm volatile("s_waitcnt lgkmcnt(0)" ::: "memory");
        float o0 = 0.f, o1 = 0.f, o2 = 0.f;
        const float4* xs4 = reinterpret_cast<const float4*>(&xsum[wv][b][0]);
        #pragma unroll
        for (int q = 0; q < 7; ++q) {
            float4 xv = xs4[q];
            int i0 = q * 4;
            o0 = fmaf(w0[i0],     xv.x, o0); o0 = fmaf(w0[i0 + 1],  xv.y, o0);
            o0 = fmaf(w0[i0 + 2], xv.z, o0); o0 = fmaf(w0[i0 + 3],  xv.w, o0);
            o1 = fmaf(w1r[i0],     xv.x, o1); o1 = fmaf(w1r[i0 + 1], xv.y, o1);
            o1 = fmaf(w1r[i0 + 2], xv.z, o1); o1 = fmaf(w1r[i0 + 3], xv.w, o1);
            o2 = fmaf(w2r[i0],     xv.x, o2); o2 = fmaf(w2r[i0 + 1], xv.y, o2);
            o2 = fmaf(w2r[i0 + 2], xv.z, o2); o2 = fmaf(w2r[i0 + 3], xv.w, o2);
        }
        {
            float2 xt = *reinterpret_cast<const float2*>(&xsum[wv][b][28]);
            o0 = fmaf(w0[28],  xt.x, o0); o0 = fmaf(w0[29],  xt.y, o0);
            o1 = fmaf(w1r[28], xt.x, o1); o1 = fmaf(w1r[29], xt.y, o1);
            o2 = fmaf(w2r[28], xt.x, o2); o2 = fmaf(w2r[29], xt.y, o2);
        }
        asm volatile("s_waitcnt lgkmcnt(0)" ::: "memory");
        if (active) {
            __half* orow = tseg + (size_t)(row - rowLo) * H + b * IB + j;
            orow[0] = __float2half(o0);
            orow[1] = __float2half(o1);
            orow[2] = __float2half(o2);
        }
    }
}

// =============== per-dst aggregation + relu + bf16-A write ===============

#define AGG_D 16

__global__ void k_aggadd(const __half* __restrict__ tseg, const int* __restrict__ dstbase,
                         float* __restrict__ buf, ushort_t* __restrict__ Abf,
                         int relu, int s0, int s1) {
    int t = threadIdx.x;
    int segBase = dstbase[s0];
    int d0 = s0 + blockIdx.x * AGG_D;
    for (int dd = 0; dd < AGG_D; ++dd) {
        int d = d0 + dd;
        if (d >= s1) break;
        int a = dstbase[d], bnd = dstbase[d + 1];
        if (t < H) {
            float acc = buf[(size_t)d * H + t];
            for (int s = a; s < bnd; ++s)
                acc += __half2float(tseg[(size_t)(s - segBase) * H + t]);
            if (relu) acc = fmaxf(acc, 0.f);
            buf[(size_t)d * H + t] = acc;
            if (Abf) Abf[(size_t)d * 160 + t] = f2bf(acc);
        } else if (t < 160) {
            if (Abf) Abf[(size_t)d * 160 + t] = 0;
        }
    }
}

// =============== launch ===============

extern "C" void kernel_launch(void* const* d_in, const int* in_sizes, int n_in,
                              void* d_out, int out_size, void* d_ws, size_t ws_size,
                              hipStream_t stream) {
    const float* node_emb = (const float*)d_in[0];
    const float* w1 = (const float*)d_in[1];
    const float* root1 = (const float*)d_in[2];
    const float* b1 = (const float*)d_in[3];
    const float* w2 = (const float*)d_in[4];
    const float* root2 = (const float*)d_in[5];
    const float* b2 = (const float*)d_in[6];
    const int* edge_index = (const int*)d_in[7];
    const int* edge_type = (const int*)d_in[8];
    int N_ = in_sizes[0] / H;
    int E_ = in_sizes[8];
    float* out = (float*)d_out;

    const int Ncells = N_ * RNUM;
    const int wtot = RNUM * BNUM * IB * IB;

    int* ws = (int*)d_ws;
    size_t off = 0;
    int* cnt      = ws + off; off += Ncells;
    int* relhist2 = ws + off; off += 64;
    int* relfill2 = ws + off; off += 64;
    size_t zero_units = off;              // memset covers cnt + relhist2 + relfill2
    int* relbase2 = ws + off; off += 64;
    int* blkN     = ws + off; off += 64;
    int* blkD     = ws + off; off += 64;
    int* blkBN    = ws + off; off += 64;
    int* blkBD    = ws + off; off += 64;
    int* dstbase  = ws + off; off += N_ + 2;
    int* segoff   = ws + off; off += Ncells;
    int* segidx   = ws + off; off += Ncells;
    int* ssrc2    = ws + off; off += E_;
    off = (off + 3) & ~(size_t)3;         // 16B align for int4
    int4* rec     = (int4*)(ws + off); off += (size_t)4 * Ncells;
    float* wt1    = (float*)(ws + off); off += wtot;
    float* wt2    = (float*)(ws + off); off += wtot;
    ushort_t* Bbf1 = (ushort_t*)(ws + off); off += 12800;   // 160*160 bf16
    ushort_t* Bbf2 = (ushort_t*)(ws + off); off += 12800;
    ushort_t* Abf  = (ushort_t*)(ws + off); off += (size_t)N_ * 160 / 2;
    float* buf1   = (float*)(ws + off); off += (size_t)N_ * H;
    __half* tseg  = (__half*)(ws + off);
    size_t tsegOffB = off * 4;

    // adaptive striping (worst-case RNUM fp16 rows per dst)
    size_t availB = (ws_size > tsegOffB) ? (ws_size - tsegOffB) : 0;
    long long dps_ll = (long long)(availB / ((size_t)RNUM * H * 2));
    int dps = (dps_ll > N_) ? N_ : (int)dps_ll;
    if (dps < 1) dps = 1;
    int nstripe = (N_ + dps - 1) / dps;

    hipMemsetAsync(cnt, 0, zero_units * 4, stream);

    k_count<<<512, 256, 0, stream>>>(edge_index, edge_type, E_, cnt);
    int nscan = (N_ + SCAN_SPAN - 1) / SCAN_SPAN;
    k_scanA<<<nscan, SCAN_BLOCK, 0, stream>>>(cnt, N_, blkN, blkD);
    k_scanB<<<1, 64, 0, stream>>>(blkN, blkD, blkBN, blkBD, nscan);
    k_scanC<<<nscan, SCAN_BLOCK, 0, stream>>>(cnt, N_, blkBN, blkBD, dstbase, segoff, segidx);
    k_scatter2<<<(E_ + 255) / 256, 256, 0, stream>>>(edge_index, edge_type, E_, segoff, ssrc2);
    k_relcnt<<<64, 256, 0, stream>>>(cnt, Ncells, relhist2);
    k_relbase<<<1, 64, 0, stream>>>(relhist2, relbase2);
    k_relassign<<<64, 256, 0, stream>>>(cnt, segoff, segidx, Ncells, relbase2, relfill2, rec);
    k_transpose_w<<<(2 * wtot + 255) / 256, 256, 0, stream>>>(w1, w2, wt1, wt2);
    k_convB<<<(2 * 160 * 160 + 255) / 256, 256, 0, stream>>>(root1, root2, Bbf1, Bbf2);
    k_convA<<<(N_ * 160 + 255) / 256, 256, 0, stream>>>(node_emb, Abf, N_);

    dim3 segGrid(64, RNUM);

    // ---- layer 1 ----
    k_rootmm<<<dim3(40, 10), 256, 0, stream>>>(Abf, Bbf1, b1, buf1, N_);
    for (int st = 0; st < nstripe; ++st) {
        int s0 = st * dps;
        int s1 = s0 + dps; if (s1 > N_) s1 = N_;
        k_seg<<<segGrid, 256, 0, stream>>>(rec, relbase2, dstbase, ssrc2, wt1, node_emb, tseg, s0, s1);
        k_aggadd<<<(s1 - s0 + AGG_D - 1) / AGG_D, 192, 0, stream>>>(tseg, dstbase, buf1, Abf, 1, s0, s1);
    }

    // ---- layer 2 ----
    k_rootmm<<<dim3(40, 10), 256, 0, stream>>>(Abf, Bbf2, b2, out, N_);
    for (int st = 0; st < nstripe; ++st) {
        int s0 = st * dps;
        int s1 = s0 + dps; if (s1 > N_) s1 = N_;
        k_seg<<<segGrid, 256, 0, stream>>>(rec, relbase2, dstbase, ssrc2, wt2, buf1, tseg, s0, s1);
        k_aggadd<<<(s1 - s0 + AGG_D - 1) / AGG_D, 192, 0, stream>>>(tseg, dstbase, out, (ushort_t*)nullptr, 0, s0, s1);
    }
}

// Round 5
// 506.151 us; speedup vs baseline: 8.6794x; 1.7245x over previous
//
#include <hip/hip_runtime.h>
#include <hip/hip_fp16.h>

#define H 150
#define RNUM 35
#define BNUM 5
#define IB 30

typedef unsigned short ushort_t;
typedef unsigned int uint_t;
using bf16x8 = __attribute__((ext_vector_type(8))) short;
using f32x4  = __attribute__((ext_vector_type(4))) float;

__device__ __forceinline__ ushort_t f2bf(float x) {
    union { float f; unsigned u; } v; v.f = x;
    unsigned u = v.u;
    return (ushort_t)((u + 0x7FFF + ((u >> 16) & 1)) >> 16);
}

// =============== preprocessing ===============

__global__ void k_count(const int* __restrict__ ei, const int* __restrict__ et,
                        int E_, int* __restrict__ cnt) {
    for (int e = blockIdx.x * blockDim.x + threadIdx.x; e < E_; e += gridDim.x * blockDim.x) {
        int d = ei[E_ + e];
        int r = et[e];
        atomicAdd(&cnt[d * RNUM + r], 1);
    }
}

#define SPT 2
#define SCAN_BLOCK 256
#define SCAN_SPAN (SPT * SCAN_BLOCK)

__global__ void k_scanA(const int* __restrict__ cnt, int N_,
                        int* __restrict__ blkN, int* __restrict__ blkD) {
    __shared__ int sn[SCAN_BLOCK], sd[SCAN_BLOCK];
    int t = threadIdx.x;
    int base = blockIdx.x * SCAN_SPAN + t * SPT;
    int tn = 0, td = 0;
    for (int k = 0; k < SPT; ++k) {
        int d = base + k;
        if (d < N_) {
            for (int r = 0; r < RNUM; ++r) {
                int c = cnt[d * RNUM + r];
                if (c) { tn++; td += c; }
            }
        }
    }
    sn[t] = tn; sd[t] = td;
    __syncthreads();
    if (t == 0) {
        int an = 0, ad = 0;
        for (int i = 0; i < SCAN_BLOCK; ++i) { an += sn[i]; ad += sd[i]; }
        blkN[blockIdx.x] = an; blkD[blockIdx.x] = ad;
    }
}

__global__ void k_scanB(const int* __restrict__ blkN, const int* __restrict__ blkD,
                        int* __restrict__ blkBN, int* __restrict__ blkBD, int nblk) {
    if (threadIdx.x == 0 && blockIdx.x == 0) {
        int an = 0, ad = 0;
        for (int i = 0; i < nblk; ++i) {
            blkBN[i] = an; blkBD[i] = ad;
            an += blkN[i]; ad += blkD[i];
        }
    }
}

__global__ void k_scanC(const int* __restrict__ cnt, int N_,
                        const int* __restrict__ blkBN, const int* __restrict__ blkBD,
                        int* __restrict__ dstbase, int* __restrict__ segoff,
                        int* __restrict__ segidx, int* __restrict__ relhist2) {
    __shared__ int sn[SCAN_BLOCK], sd[SCAN_BLOCK];
    __shared__ int lhist[RNUM];
    int t = threadIdx.x;
    for (int i = t; i < RNUM; i += SCAN_BLOCK) lhist[i] = 0;
    int base = blockIdx.x * SCAN_SPAN + t * SPT;
    int tn = 0, td = 0;
    for (int k = 0; k < SPT; ++k) {
        int d = base + k;
        if (d < N_) {
            for (int r = 0; r < RNUM; ++r) {
                int c = cnt[d * RNUM + r];
                if (c) { tn++; td += c; }
            }
        }
    }
    sn[t] = tn; sd[t] = td;
    __syncthreads();
    if (t == 0) {
        int an = blkBN[blockIdx.x], ad = blkBD[blockIdx.x];
        for (int i = 0; i < SCAN_BLOCK; ++i) {
            int a = sn[i], b = sd[i];
            sn[i] = an; sd[i] = ad;
            an += a; ad += b;
        }
    }
    __syncthreads();
    int sb = sn[t], eb = sd[t];
    for (int k = 0; k < SPT; ++k) {
        int d = base + k;
        if (d < N_) {
            dstbase[d] = sb;
            for (int r = 0; r < RNUM; ++r) {
                int cell = d * RNUM + r;
                int c = cnt[cell];
                segoff[cell] = eb;
                if (c) { segidx[cell] = sb; sb++; eb += c; atomicAdd(&lhist[r], 1); }
            }
            if (d == N_ - 1) dstbase[N_] = sb;
        }
    }
    __syncthreads();
    for (int i = t; i < RNUM; i += SCAN_BLOCK)
        if (lhist[i]) atomicAdd(&relhist2[i], lhist[i]);
}

__global__ void k_relbase(const int* __restrict__ relhist2, int* __restrict__ relbase2) {
    if (threadIdx.x == 0 && blockIdx.x == 0) {
        int a = 0;
        for (int r = 0; r < RNUM; ++r) { relbase2[r] = a; a += relhist2[r]; }
        relbase2[RNUM] = a;
    }
}

__global__ void k_scatter2(const int* __restrict__ ei, const int* __restrict__ et,
                           int E_, int* __restrict__ segoff, int* __restrict__ ssrc2) {
    int e = blockIdx.x * blockDim.x + threadIdx.x;
    if (e >= E_) return;
    int r = et[e];
    int d = ei[E_ + e];
    int pos = atomicAdd(&segoff[d * RNUM + r], 1);
    ssrc2[pos] = ei[e];
}

__global__ void k_relassign(const int* __restrict__ cnt, const int* __restrict__ segoff,
                            const int* __restrict__ segidx, int Ncells,
                            const int* __restrict__ relbase2, int* __restrict__ relfill2,
                            int4* __restrict__ rec) {
    __shared__ int lh[RNUM];
    __shared__ int lbase[RNUM];
    for (int i = threadIdx.x; i < RNUM; i += blockDim.x) lh[i] = 0;
    __syncthreads();
    const int stride = gridDim.x * blockDim.x;
    for (int cell = blockIdx.x * blockDim.x + threadIdx.x; cell < Ncells; cell += stride)
        if (cnt[cell]) atomicAdd(&lh[cell % RNUM], 1);
    __syncthreads();
    for (int i = threadIdx.x; i < RNUM; i += blockDim.x) {
        int c = lh[i];
        lbase[i] = relbase2[i] + (c ? atomicAdd(&relfill2[i], c) : 0);
        lh[i] = 0;
    }
    __syncthreads();
    for (int cell = blockIdx.x * blockDim.x + threadIdx.x; cell < Ncells; cell += stride) {
        int c = cnt[cell];
        if (c) {
            int r = cell % RNUM;
            int pos = lbase[r] + atomicAdd(&lh[r], 1);
            rec[pos] = make_int4(segidx[cell], segoff[cell] - c, c, 0);
        }
    }
}

// W in MFMA-B-fragment order, bf16, K padded 30->32 with zeros
__global__ void k_prepw(const float* __restrict__ w1, const float* __restrict__ w2,
                        ushort_t* __restrict__ wb1, ushort_t* __restrict__ wb2) {
    const int tot = RNUM * BNUM * 2 * 16 * 32;
    int idx = blockIdx.x * blockDim.x + threadIdx.x;
    if (idx >= 2 * tot) return;
    const float* w = (idx < tot) ? w1 : w2;
    ushort_t* wb = (idx < tot) ? wb1 : wb2;
    int q = (idx < tot) ? idx : idx - tot;
    int kj = q & 7;
    int kg = (q >> 3) & 3;
    int cl = (q >> 5) & 15;
    int nh = (q >> 9) & 1;
    int rb = q >> 10;
    int k = kg * 8 + kj;
    int col = nh * 16 + cl;
    ushort_t v = 0;
    if (k < IB && col < IB) v = f2bf(w[(rb * IB + k) * IB + col]);
    wb[q] = v;
}

__global__ void k_convA(const float* __restrict__ x, ushort_t* __restrict__ Abf, int N_) {
    int i = blockIdx.x * blockDim.x + threadIdx.x;
    if (i >= N_ * 160) return;
    int n = i / 160, c = i - n * 160;
    Abf[i] = (c < H) ? f2bf(x[n * H + c]) : 0;
}

__global__ void k_convB(const float* __restrict__ r1, const float* __restrict__ r2,
                        ushort_t* __restrict__ B1, ushort_t* __restrict__ B2) {
    int i = blockIdx.x * blockDim.x + threadIdx.x;
    if (i >= 2 * 160 * 160) return;
    const float* src = (i < 160 * 160) ? r1 : r2;
    ushort_t* dst = (i < 160 * 160) ? B1 : B2;
    int k = (i < 160 * 160) ? i : i - 160 * 160;
    int row = k / 160, col = k - row * 160;
    dst[k] = (row < H && col < H) ? f2bf(src[row * H + col]) : 0;
}

__global__ __launch_bounds__(256) void k_rootmm(const ushort_t* __restrict__ Abf,
                                                const ushort_t* __restrict__ Bbf,
                                                const float* __restrict__ bias,
                                                float* __restrict__ Cout, int N_) {
    int nt = blockIdx.y;
    int wv = threadIdx.x >> 6, l = threadIdx.x & 63;
    int lr = l & 15, lk = l >> 4;
    bf16x8 bfr[5];
    #pragma unroll
    for (int ks = 0; ks < 5; ++ks) {
        #pragma unroll
        for (int j = 0; j < 8; ++j)
            bfr[ks][j] = (short)Bbf[(ks * 32 + lk * 8 + j) * 160 + nt * 16 + lr];
    }
    int mtiles = N_ / 16;
    int col = nt * 16 + lr;
    float bv = (col < H) ? bias[col] : 0.f;
    for (int mt = blockIdx.x * 4 + wv; mt < mtiles; mt += gridDim.x * 4) {
        f32x4 acc = {0.f, 0.f, 0.f, 0.f};
        const ushort_t* arow = Abf + (size_t)(mt * 16 + lr) * 160 + lk * 8;
        #pragma unroll
        for (int ks = 0; ks < 5; ++ks) {
            bf16x8 af = *reinterpret_cast<const bf16x8*>(arow + ks * 32);
            acc = __builtin_amdgcn_mfma_f32_16x16x32_bf16(af, bfr[ks], acc, 0, 0, 0);
        }
        if (col < H) {
            #pragma unroll
            for (int reg = 0; reg < 4; ++reg)
                Cout[(size_t)(mt * 16 + lk * 4 + reg) * H + col] = acc[reg] + bv;
        }
    }
}

// =============== per-segment transform via MFMA (wave-private, no barriers) ===============

#define ASTRIDE 168

__global__ __launch_bounds__(256, 4)
void k_seg(const int4* __restrict__ rec, const int* __restrict__ relbase2,
           const int* __restrict__ ssrc2, const ushort_t* __restrict__ wbf,
           const float* __restrict__ xin, __half* __restrict__ tseg,
           const int* __restrict__ rowLoP, const int* __restrict__ rowHiP) {
    __shared__ ushort_t Abuf[4][16 * ASTRIDE];
    int rowLo = rowLoP[0], rowHi = rowHiP[0];
    int r = blockIdx.y;
    int base = relbase2[r];
    int nseg = relbase2[r + 1] - base;
    int t = threadIdx.x, wv = t >> 6, l = t & 63;
    int lr = l & 15, kg = l >> 4;

    bf16x8 bfr[BNUM][2];
    #pragma unroll
    for (int b = 0; b < BNUM; ++b)
        #pragma unroll
        for (int nh = 0; nh < 2; ++nh)
            bfr[b][nh] = *reinterpret_cast<const bf16x8*>(
                wbf + ((size_t)((r * BNUM + b) * 2 + nh) * 512) + lr * 32 + kg * 8);

    {
        uint_t* az = reinterpret_cast<uint_t*>(&Abuf[wv][0]);
        for (int i = l; i < 16 * ASTRIDE / 2; i += 64) az[i] = 0;
    }

    int o0 = (l / 30) * 32 + (l % 30);
    int o1 = ((l + 64) / 30) * 32 + ((l + 64) % 30);
    int o2 = ((l + 128) / 30) * 32 + ((l + 128) % 30);

    int ntile = (nseg + 15) >> 4;
    for (int ti = blockIdx.x * 4 + wv; ti < ntile; ti += gridDim.x * 4) {
        int sbeg = ti << 4;
        int4 myrec = make_int4(0x7fffffff, 0, 0, 0);
        if (l < 16 && sbeg + l < nseg) myrec = rec[base + sbeg + l];

        for (int s = 0; s < 16; ++s) {
            int row = __builtin_amdgcn_readfirstlane(__shfl(myrec.x, s));
            if (row < rowLo || row >= rowHi) continue;
            int eo = __builtin_amdgcn_readfirstlane(__shfl(myrec.y, s));
            int c  = __builtin_amdgcn_readfirstlane(__shfl(myrec.z, s));
            float a0 = 0.f, a1 = 0.f, a2 = 0.f;
            for (int k = 0; k < c; ++k) {
                int src = ssrc2[eo + k];
                const float* xr = xin + (size_t)src * H;
                a0 += xr[l];
                a1 += xr[l + 64];
                if (l < 22) a2 += xr[l + 128];
            }
            float inv = 1.0f / (float)c;
            ushort_t* Aw = &Abuf[wv][s * ASTRIDE];
            Aw[o0] = f2bf(a0 * inv);
            Aw[o1] = f2bf(a1 * inv);
            if (l < 22) Aw[o2] = f2bf(a2 * inv);
        }

        int rg[4]; bool rok[4];
        #pragma unroll
        for (int q = 0; q < 4; ++q) {
            rg[q] = __shfl(myrec.x, kg * 4 + q);
            rok[q] = (rg[q] >= rowLo) && (rg[q] < rowHi);
        }

        #pragma unroll
        for (int b = 0; b < BNUM; ++b) {
            bf16x8 af = *reinterpret_cast<const bf16x8*>(
                &Abuf[wv][lr * ASTRIDE + b * 32 + kg * 8]);
            f32x4 acc0 = {0.f, 0.f, 0.f, 0.f};
            f32x4 acc1 = {0.f, 0.f, 0.f, 0.f};
            acc0 = __builtin_amdgcn_mfma_f32_16x16x32_bf16(af, bfr[b][0], acc0, 0, 0, 0);
            acc1 = __builtin_amdgcn_mfma_f32_16x16x32_bf16(af, bfr[b][1], acc1, 0, 0, 0);
            #pragma unroll
            for (int q = 0; q < 4; ++q) {
                if (rok[q]) {
                    __half* orow = tseg + (size_t)(rg[q] - rowLo) * H + b * IB;
                    orow[lr] = __float2half(acc0[q]);
                    if (lr < 14) orow[16 + lr] = __float2half(acc1[q]);
                }
            }
        }
    }
}

__global__ __launch_bounds__(256)
void k_aggadd(const __half* __restrict__ tseg, const int* __restrict__ dstbase,
              float* __restrict__ buf, ushort_t* __restrict__ Abf,
              int relu, int s0, int s1) {
    int t = threadIdx.x, wv = t >> 6, l = t & 63;
    int segBase = dstbase[s0];
    for (int d = s0 + blockIdx.x * 4 + wv; d < s1; d += gridDim.x * 4) {
        int a = dstbase[d], bnd = dstbase[d + 1];
        float* brow = buf + (size_t)d * H;
        float2 acc0 = *reinterpret_cast<const float2*>(brow + 2 * l);
        float2 acc1 = make_float2(0.f, 0.f);
        if (l < 11) acc1 = *reinterpret_cast<const float2*>(brow + 128 + 2 * l);
        for (int s = a; s < bnd; ++s) {
            const __half2* trow = reinterpret_cast<const __half2*>(
                tseg + (size_t)(s - segBase) * H);
            float2 v = __half22float2(trow[l]);
            acc0.x += v.x; acc0.y += v.y;
            if (l < 11) {
                float2 v1 = __half22float2(trow[64 + l]);
                acc1.x += v1.x; acc1.y += v1.y;
            }
        }
        if (relu) {
            acc0.x = fmaxf(acc0.x, 0.f); acc0.y = fmaxf(acc0.y, 0.f);
            acc1.x = fmaxf(acc1.x, 0.f); acc1.y = fmaxf(acc1.y, 0.f);
        }
        *reinterpret_cast<float2*>(brow + 2 * l) = acc0;
        if (l < 11) *reinterpret_cast<float2*>(brow + 128 + 2 * l) = acc1;
        if (Abf) {
            ushort_t* arow = Abf + (size_t)d * 160;
            uint_t p0 = (uint_t)f2bf(acc0.x) | ((uint_t)f2bf(acc0.y) << 16);
            *reinterpret_cast<uint_t*>(arow + 2 * l) = p0;
            if (l < 11) {
                uint_t p1 = (uint_t)f2bf(acc1.x) | ((uint_t)f2bf(acc1.y) << 16);
                *reinterpret_cast<uint_t*>(arow + 128 + 2 * l) = p1;
            }
            if (l < 5) *reinterpret_cast<uint_t*>(arow + 150 + 2 * l) = 0;
        }
    }
}

extern "C" void kernel_launch(void* const* d_in, const int* in_sizes, int n_in,
                              void* d_out, int out_size, void* d_ws, size_t ws_size,
                              hipStream_t stream) {
    const float* node_emb = (const float*)d_in[0];
    const float* w1 = (const float*)d_in[1];
    const float* root1 = (const float*)d_in[2];
    const float* b1 = (const float*)d_in[3];
    const float* w2 = (const float*)d_in[4];
    const float* root2 = (const float*)d_in[5];
    const float* b2 = (const float*)d_in[6];
    const int* edge_index = (const int*)d_in[7];
    const int* edge_type = (const int*)d_in[8];
    int N_ = in_sizes[0] / H;
    int E_ = in_sizes[8];
    float* out = (float*)d_out;

    const int Ncells = N_ * RNUM;
    const int wbtot = RNUM * BNUM * 2 * 16 * 32;

    int* ws = (int*)d_ws;
    size_t off = 0;
    int* cnt      = ws + off; off += Ncells;
    int* relhist2 = ws + off; off += 64;
    int* relfill2 = ws + off; off += 64;
    size_t zero_units = off;
    int* relbase2 = ws + off; off += 64;
    int* blkN     = ws + off; off += 64;
    int* blkD     = ws + off; off += 64;
    int* blkBN    = ws + off; off += 64;
    int* blkBD    = ws + off; off += 64;
    int* dstbase  = ws + off; off += N_ + 2;
    int* segoff   = ws + off; off += Ncells;
    int* segidx   = ws + off; off += Ncells;
    int* ssrc2    = ws + off; off += E_;
    off = (off + 3) & ~(size_t)3;
    int4* rec     = (int4*)(ws + off); off += (size_t)4 * Ncells;
    ushort_t* wbf1 = (ushort_t*)(ws + off); off += wbtot / 2;
    ushort_t* wbf2 = (ushort_t*)(ws + off); off += wbtot / 2;
    ushort_t* Bbf1 = (ushort_t*)(ws + off); off += 12800;
    ushort_t* Bbf2 = (ushort_t*)(ws + off); off += 12800;
    ushort_t* Abf  = (ushort_t*)(ws + off); off += (size_t)N_ * 160 / 2;
    float* buf1   = (float*)(ws + off); off += (size_t)N_ * H;
    __half* tseg  = (__half*)(ws + off);
    size_t tsegOffB = off * 4;

    size_t availB = (ws_size > tsegOffB) ? (ws_size - tsegOffB) : 0;
    long long dps_ll = (long long)(availB / ((size_t)RNUM * H * 2));
    int dps = (dps_ll > N_) ? N_ : (int)dps_ll;
    if (dps < 1) dps = 1;
    int nstripe = (N_ + dps - 1) / dps;

    hipMemsetAsync(cnt, 0, zero_units * 4, stream);

    k_count<<<512, 256, 0, stream>>>(edge_index, edge_type, E_, cnt);
    int nscan = (N_ + SCAN_SPAN - 1) / SCAN_SPAN;
    k_scanA<<<nscan, SCAN_BLOCK, 0, stream>>>(cnt, N_, blkN, blkD);
    k_scanB<<<1, 64, 0, stream>>>(blkN, blkD, blkBN, blkBD, nscan);
    k_scanC<<<nscan, SCAN_BLOCK, 0, stream>>>(cnt, N_, blkBN, blkBD, dstbase, segoff,
                                              segidx, relhist2);
    k_relbase<<<1, 64, 0, stream>>>(relhist2, relbase2);
    k_scatter2<<<(E_ + 255) / 256, 256, 0, stream>>>(edge_index, edge_type, E_, segoff, ssrc2);
    k_relassign<<<64, 256, 0, stream>>>(cnt, segoff, segidx, Ncells, relbase2, relfill2, rec);
    k_prepw<<<(2 * wbtot + 255) / 256, 256, 0, stream>>>(w1, w2, wbf1, wbf2);
    k_convB<<<(2 * 160 * 160 + 255) / 256, 256, 0, stream>>>(root1, root2, Bbf1, Bbf2);
    k_convA<<<(N_ * 160 + 255) / 256, 256, 0, stream>>>(node_emb, Abf, N_);

    dim3 segGrid(64, RNUM);

    // layer 1
    k_rootmm<<<dim3(40, 10), 256, 0, stream>>>(Abf, Bbf1, b1, buf1, N_);
    for (int st = 0; st < nstripe; ++st) {
        int s0 = st * dps;
        int s1 = s0 + dps; if (s1 > N_) s1 = N_;
        k_seg<<<segGrid, 256, 0, stream>>>(rec, relbase2, ssrc2, wbf1, node_emb, tseg,
                                           dstbase + s0, dstbase + s1);
        k_aggadd<<<1280, 256, 0, stream>>>(tseg, dstbase, buf1, Abf, 1, s0, s1);
    }

    // layer 2
    k_rootmm<<<dim3(40, 10), 256, 0, stream>>>(Abf, Bbf2, b2, out, N_);
    for (int st = 0; st < nstripe; ++st) {
        int s0 = st * dps;
        int s1 = s0 + dps; if (s1 > N_) s1 = N_;
        k_seg<<<segGrid, 256, 0, stream>>>(rec, relbase2, ssrc2, wbf2, buf1, tseg,
                                           dstbase + s0, dstbase + s1);
        k_aggadd<<<1280, 256, 0, stream>>>(tseg, dstbase, out, (ushort_t*)nullptr, 0, s0, s1);
    }
}

// Round 6
// 455.463 us; speedup vs baseline: 9.6453x; 1.1113x over previous
//
#include <hip/hip_runtime.h>
#include <hip/hip_fp16.h>

#define H 150
#define RNUM 35
#define BNUM 5
#define IB 30

typedef unsigned short ushort_t;
typedef unsigned int uint_t;
using bf16x8 = __attribute__((ext_vector_type(8))) short;
using f32x4  = __attribute__((ext_vector_type(4))) float;

__device__ __forceinline__ ushort_t f2bf(float x) {
    union { float f; unsigned u; } v; v.f = x;
    unsigned u = v.u;
    return (ushort_t)((u + 0x7FFF + ((u >> 16) & 1)) >> 16);
}
__device__ __forceinline__ float bfLo(uint_t u) {
    union { unsigned u; float f; } v; v.u = u << 16; return v.f;
}
__device__ __forceinline__ float bfHi(uint_t u) {
    union { unsigned u; float f; } v; v.u = u & 0xffff0000u; return v.f;
}

// =============== preprocessing ===============

__global__ void k_count(const int* __restrict__ ei, const int* __restrict__ et,
                        int E_, int* __restrict__ cnt) {
    for (int e = blockIdx.x * blockDim.x + threadIdx.x; e < E_; e += gridDim.x * blockDim.x) {
        int d = ei[E_ + e];
        int r = et[e];
        atomicAdd(&cnt[d * RNUM + r], 1);
    }
}

#define SPT 2
#define SCAN_BLOCK 256
#define SCAN_SPAN (SPT * SCAN_BLOCK)

__global__ void k_scanA(const int* __restrict__ cnt, int N_,
                        int* __restrict__ blkN, int* __restrict__ blkD) {
    __shared__ int sn[SCAN_BLOCK], sd[SCAN_BLOCK];
    int t = threadIdx.x;
    int base = blockIdx.x * SCAN_SPAN + t * SPT;
    int tn = 0, td = 0;
    for (int k = 0; k < SPT; ++k) {
        int d = base + k;
        if (d < N_) {
            for (int r = 0; r < RNUM; ++r) {
                int c = cnt[d * RNUM + r];
                if (c) { tn++; td += c; }
            }
        }
    }
    sn[t] = tn; sd[t] = td;
    __syncthreads();
    if (t == 0) {
        int an = 0, ad = 0;
        for (int i = 0; i < SCAN_BLOCK; ++i) { an += sn[i]; ad += sd[i]; }
        blkN[blockIdx.x] = an; blkD[blockIdx.x] = ad;
    }
}

__global__ void k_scanB(const int* __restrict__ blkN, const int* __restrict__ blkD,
                        int* __restrict__ blkBN, int* __restrict__ blkBD, int nblk) {
    if (threadIdx.x == 0 && blockIdx.x == 0) {
        int an = 0, ad = 0;
        for (int i = 0; i < nblk; ++i) {
            blkBN[i] = an; blkBD[i] = ad;
            an += blkN[i]; ad += blkD[i];
        }
    }
}

__global__ void k_scanC(const int* __restrict__ cnt, int N_,
                        const int* __restrict__ blkBN, const int* __restrict__ blkBD,
                        int* __restrict__ dstbase, int* __restrict__ segoff,
                        int* __restrict__ segidx, int* __restrict__ relhist2) {
    __shared__ int sn[SCAN_BLOCK], sd[SCAN_BLOCK];
    __shared__ int lhist[RNUM];
    int t = threadIdx.x;
    for (int i = t; i < RNUM; i += SCAN_BLOCK) lhist[i] = 0;
    int base = blockIdx.x * SCAN_SPAN + t * SPT;
    int tn = 0, td = 0;
    for (int k = 0; k < SPT; ++k) {
        int d = base + k;
        if (d < N_) {
            for (int r = 0; r < RNUM; ++r) {
                int c = cnt[d * RNUM + r];
                if (c) { tn++; td += c; }
            }
        }
    }
    sn[t] = tn; sd[t] = td;
    __syncthreads();
    if (t == 0) {
        int an = blkBN[blockIdx.x], ad = blkBD[blockIdx.x];
        for (int i = 0; i < SCAN_BLOCK; ++i) {
            int a = sn[i], b = sd[i];
            sn[i] = an; sd[i] = ad;
            an += a; ad += b;
        }
    }
    __syncthreads();
    int sb = sn[t], eb = sd[t];
    for (int k = 0; k < SPT; ++k) {
        int d = base + k;
        if (d < N_) {
            dstbase[d] = sb;
            for (int r = 0; r < RNUM; ++r) {
                int cell = d * RNUM + r;
                int c = cnt[cell];
                segoff[cell] = eb;
                if (c) { segidx[cell] = sb; sb++; eb += c; atomicAdd(&lhist[r], 1); }
            }
            if (d == N_ - 1) dstbase[N_] = sb;
        }
    }
    __syncthreads();
    for (int i = t; i < RNUM; i += SCAN_BLOCK)
        if (lhist[i]) atomicAdd(&relhist2[i], lhist[i]);
}

// relbase2 (segment base per rel) + tprefix (tile base per rel, tiles of 16 segs)
__global__ void k_relbase(const int* __restrict__ relhist2, int* __restrict__ relbase2,
                          int* __restrict__ tprefix) {
    if (threadIdx.x == 0 && blockIdx.x == 0) {
        int a = 0, tp = 0;
        for (int r = 0; r < RNUM; ++r) {
            relbase2[r] = a; tprefix[r] = tp;
            a += relhist2[r];
            tp += (relhist2[r] + 15) >> 4;
        }
        relbase2[RNUM] = a; tprefix[RNUM] = tp;
    }
}

__global__ void k_scatter2(const int* __restrict__ ei, const int* __restrict__ et,
                           int E_, int* __restrict__ segoff, int* __restrict__ ssrc2) {
    int e = blockIdx.x * blockDim.x + threadIdx.x;
    if (e >= E_) return;
    int r = et[e];
    int d = ei[E_ + e];
    int pos = atomicAdd(&segoff[d * RNUM + r], 1);
    ssrc2[pos] = ei[e];
}

__global__ void k_relassign(const int* __restrict__ cnt, const int* __restrict__ segoff,
                            const int* __restrict__ segidx, int Ncells,
                            const int* __restrict__ relbase2, int* __restrict__ relfill2,
                            int4* __restrict__ rec) {
    __shared__ int lh[RNUM];
    __shared__ int lbase[RNUM];
    for (int i = threadIdx.x; i < RNUM; i += blockDim.x) lh[i] = 0;
    __syncthreads();
    const int stride = gridDim.x * blockDim.x;
    for (int cell = blockIdx.x * blockDim.x + threadIdx.x; cell < Ncells; cell += stride)
        if (cnt[cell]) atomicAdd(&lh[cell % RNUM], 1);
    __syncthreads();
    for (int i = threadIdx.x; i < RNUM; i += blockDim.x) {
        int c = lh[i];
        lbase[i] = relbase2[i] + (c ? atomicAdd(&relfill2[i], c) : 0);
        lh[i] = 0;
    }
    __syncthreads();
    for (int cell = blockIdx.x * blockDim.x + threadIdx.x; cell < Ncells; cell += stride) {
        int c = cnt[cell];
        if (c) {
            int r = cell % RNUM;
            int pos = lbase[r] + atomicAdd(&lh[r], 1);
            rec[pos] = make_int4(segidx[cell], segoff[cell] - c, c, 0);
        }
    }
}

// W in MFMA-B-fragment order, bf16, K padded 30->32 with zeros
__global__ void k_prepw(const float* __restrict__ w1, const float* __restrict__ w2,
                        ushort_t* __restrict__ wb1, ushort_t* __restrict__ wb2) {
    const int tot = RNUM * BNUM * 2 * 16 * 32;
    int idx = blockIdx.x * blockDim.x + threadIdx.x;
    if (idx >= 2 * tot) return;
    const float* w = (idx < tot) ? w1 : w2;
    ushort_t* wb = (idx < tot) ? wb1 : wb2;
    int q = (idx < tot) ? idx : idx - tot;
    int kj = q & 7;
    int kg = (q >> 3) & 3;
    int cl = (q >> 5) & 15;
    int nh = (q >> 9) & 1;
    int rb = q >> 10;
    int k = kg * 8 + kj;
    int col = nh * 16 + cl;
    ushort_t v = 0;
    if (k < IB && col < IB) v = f2bf(w[(rb * IB + k) * IB + col]);
    wb[q] = v;
}

__global__ void k_convA(const float* __restrict__ x, ushort_t* __restrict__ xbf, int N_) {
    int i = blockIdx.x * blockDim.x + threadIdx.x;
    if (i >= N_ * 160) return;
    int n = i / 160, c = i - n * 160;
    xbf[i] = (c < H) ? f2bf(x[n * H + c]) : 0;
}

__global__ void k_convB(const float* __restrict__ r1, const float* __restrict__ r2,
                        ushort_t* __restrict__ B1, ushort_t* __restrict__ B2) {
    int i = blockIdx.x * blockDim.x + threadIdx.x;
    if (i >= 2 * 160 * 160) return;
    const float* src = (i < 160 * 160) ? r1 : r2;
    ushort_t* dst = (i < 160 * 160) ? B1 : B2;
    int k = (i < 160 * 160) ? i : i - 160 * 160;
    int row = k / 160, col = k - row * 160;
    dst[k] = (row < H && col < H) ? f2bf(src[row * H + col]) : 0;
}

__global__ __launch_bounds__(256) void k_rootmm(const ushort_t* __restrict__ Abf,
                                                const ushort_t* __restrict__ Bbf,
                                                const float* __restrict__ bias,
                                                float* __restrict__ Cout, int N_) {
    int nt = blockIdx.y;
    int wv = threadIdx.x >> 6, l = threadIdx.x & 63;
    int lr = l & 15, lk = l >> 4;
    bf16x8 bfr[5];
    #pragma unroll
    for (int ks = 0; ks < 5; ++ks) {
        #pragma unroll
        for (int j = 0; j < 8; ++j)
            bfr[ks][j] = (short)Bbf[(ks * 32 + lk * 8 + j) * 160 + nt * 16 + lr];
    }
    int mtiles = N_ / 16;
    int col = nt * 16 + lr;
    float bv = (col < H) ? bias[col] : 0.f;
    for (int mt = blockIdx.x * 4 + wv; mt < mtiles; mt += gridDim.x * 4) {
        f32x4 acc = {0.f, 0.f, 0.f, 0.f};
        const ushort_t* arow = Abf + (size_t)(mt * 16 + lr) * 160 + lk * 8;
        #pragma unroll
        for (int ks = 0; ks < 5; ++ks) {
            bf16x8 af = *reinterpret_cast<const bf16x8*>(arow + ks * 32);
            acc = __builtin_amdgcn_mfma_f32_16x16x32_bf16(af, bfr[ks], acc, 0, 0, 0);
        }
        if (col < H) {
            #pragma unroll
            for (int reg = 0; reg < 4; ++reg)
                Cout[(size_t)(mt * 16 + lk * 4 + reg) * H + col] = acc[reg] + bv;
        }
    }
}

// =============== per-segment transform via MFMA, bf16 gather, global tile list ===============

#define ASTRIDE 168

__global__ __launch_bounds__(256, 4)
void k_seg(const int4* __restrict__ rec, const int* __restrict__ relbase2,
           const int* __restrict__ tprefix,
           const int* __restrict__ ssrc2, const ushort_t* __restrict__ wbf,
           const ushort_t* __restrict__ xbf, __half* __restrict__ tseg,
           const int* __restrict__ rowLoP, const int* __restrict__ rowHiP) {
    __shared__ ushort_t Abuf[4][16 * ASTRIDE];
    __shared__ int relb[RNUM + 1], tpre[RNUM + 1];
    int t = threadIdx.x, wv = t >> 6, l = t & 63;
    int lr = l & 15, kg = l >> 4;
    if (t < RNUM + 1) { relb[t] = relbase2[t]; tpre[t] = tprefix[t]; }
    __syncthreads();
    int rowLo = rowLoP[0], rowHi = rowHiP[0];
    int ntile_tot = tpre[RNUM];

    // zero entire wave A-region once (covers K-pad cols; gather rewrites data cols)
    {
        uint_t* az = reinterpret_cast<uint_t*>(&Abuf[wv][0]);
        for (int i = l; i < 16 * ASTRIDE / 2; i += 64) az[i] = 0;
    }

    // packed-pair LDS offsets (uint units): elem pair (2l,2l+1) and (128+2l,129+2l)
    int i0 = 2 * l;
    int uA = (i0 / 30) * 16 + (i0 % 30) / 2 ? 0 : 0;  // placeholder, computed below
    uA = ((i0 / 30) * 32 + (i0 % 30)) >> 1;
    int i1 = 128 + 2 * l;
    int uB = ((i1 / 30) * 32 + (i1 % 30)) >> 1;        // valid for l < 11

    for (int ti = blockIdx.x * 4 + wv; ti < ntile_tot; ti += gridDim.x * 4) {
        // binary search relation: tpre[r] <= ti < tpre[r+1]  (wave-uniform)
        int r_lo = 0, r_hi = RNUM;
        while (r_hi - r_lo > 1) {
            int m = (r_lo + r_hi) >> 1;
            if (tpre[m] <= ti) r_lo = m; else r_hi = m;
        }
        int r = r_lo;
        int base = relb[r];
        int nseg = relb[r + 1] - base;
        int sbeg = (ti - tpre[r]) << 4;

        // W fragments for this relation (L2-hot)
        bf16x8 bfr[BNUM][2];
        #pragma unroll
        for (int b = 0; b < BNUM; ++b)
            #pragma unroll
            for (int nh = 0; nh < 2; ++nh)
                bfr[b][nh] = *reinterpret_cast<const bf16x8*>(
                    wbf + ((size_t)((r * BNUM + b) * 2 + nh) * 512) + lr * 32 + kg * 8);

        int4 myrec = make_int4(0x7fffffff, 0, 1, 0);
        if (l < 16 && sbeg + l < nseg) myrec = rec[base + sbeg + l];

        // ---- bf16 gather + mean + packed LDS stage ----
        uint_t* Au = reinterpret_cast<uint_t*>(&Abuf[wv][0]);
        for (int s = 0; s < 16; ++s) {
            int row = __builtin_amdgcn_readfirstlane(__shfl(myrec.x, s));
            if (row < rowLo || row >= rowHi) continue;
            int eo = __builtin_amdgcn_readfirstlane(__shfl(myrec.y, s));
            int c  = __builtin_amdgcn_readfirstlane(__shfl(myrec.z, s));
            float a0 = 0.f, a1 = 0.f, a2 = 0.f, a3 = 0.f;
            for (int k = 0; k < c; ++k) {
                int src = ssrc2[eo + k];
                const uint_t* rowU = reinterpret_cast<const uint_t*>(xbf + (size_t)src * 160);
                uint_t u0 = rowU[l];
                a0 += bfLo(u0); a1 += bfHi(u0);
                if (l < 11) {
                    uint_t u1 = rowU[64 + l];
                    a2 += bfLo(u1); a3 += bfHi(u1);
                }
            }
            float inv = 1.0f / (float)c;
            uint_t p0 = (uint_t)f2bf(a0 * inv) | ((uint_t)f2bf(a1 * inv) << 16);
            Au[s * 84 + uA] = p0;
            if (l < 11) {
                uint_t p1 = (uint_t)f2bf(a2 * inv) | ((uint_t)f2bf(a3 * inv) << 16);
                Au[s * 84 + uB] = p1;
            }
        }

        int rg[4]; bool rok[4];
        #pragma unroll
        for (int q = 0; q < 4; ++q) {
            rg[q] = __shfl(myrec.x, kg * 4 + q);
            rok[q] = (rg[q] >= rowLo) && (rg[q] < rowHi);
        }

        // ---- MFMA transform + fp16 store (invalid rows store-masked) ----
        #pragma unroll
        for (int b = 0; b < BNUM; ++b) {
            bf16x8 af = *reinterpret_cast<const bf16x8*>(
                &Abuf[wv][lr * ASTRIDE + b * 32 + kg * 8]);
            f32x4 acc0 = {0.f, 0.f, 0.f, 0.f};
            f32x4 acc1 = {0.f, 0.f, 0.f, 0.f};
            acc0 = __builtin_amdgcn_mfma_f32_16x16x32_bf16(af, bfr[b][0], acc0, 0, 0, 0);
            acc1 = __builtin_amdgcn_mfma_f32_16x16x32_bf16(af, bfr[b][1], acc1, 0, 0, 0);
            #pragma unroll
            for (int q = 0; q < 4; ++q) {
                if (rok[q]) {
                    __half* orow = tseg + (size_t)(rg[q] - rowLo) * H + b * IB;
                    orow[lr] = __float2half(acc0[q]);
                    if (lr < 14) orow[16 + lr] = __float2half(acc1[q]);
                }
            }
        }
    }
}

// =============== per-dst aggregation: acc = rootsrc + sum(tseg rows); optional relu/out/Abf ===============

__global__ __launch_bounds__(256)
void k_aggadd(const __half* __restrict__ tseg, const int* __restrict__ dstbase,
              const float* __restrict__ rootsrc, float* __restrict__ fout,
              ushort_t* __restrict__ Abf, int relu, int s0, int s1) {
    int t = threadIdx.x, wv = t >> 6, l = t & 63;
    int segBase = dstbase[s0];
    for (int d = s0 + blockIdx.x * 4 + wv; d < s1; d += gridDim.x * 4) {
        int a = dstbase[d], bnd = dstbase[d + 1];
        const float* brow = rootsrc + (size_t)d * H;
        float2 acc0 = *reinterpret_cast<const float2*>(brow + 2 * l);
        float2 acc1 = make_float2(0.f, 0.f);
        if (l < 11) acc1 = *reinterpret_cast<const float2*>(brow + 128 + 2 * l);
        for (int s = a; s < bnd; ++s) {
            const __half2* trow = reinterpret_cast<const __half2*>(
                tseg + (size_t)(s - segBase) * H);
            float2 v = __half22float2(trow[l]);
            acc0.x += v.x; acc0.y += v.y;
            if (l < 11) {
                float2 v1 = __half22float2(trow[64 + l]);
                acc1.x += v1.x; acc1.y += v1.y;
            }
        }
        if (relu) {
            acc0.x = fmaxf(acc0.x, 0.f); acc0.y = fmaxf(acc0.y, 0.f);
            acc1.x = fmaxf(acc1.x, 0.f); acc1.y = fmaxf(acc1.y, 0.f);
        }
        if (fout) {
            float* frow = fout + (size_t)d * H;
            *reinterpret_cast<float2*>(frow + 2 * l) = acc0;
            if (l < 11) *reinterpret_cast<float2*>(frow + 128 + 2 * l) = acc1;
        }
        if (Abf) {
            ushort_t* arow = Abf + (size_t)d * 160;
            uint_t p0 = (uint_t)f2bf(acc0.x) | ((uint_t)f2bf(acc0.y) << 16);
            *reinterpret_cast<uint_t*>(arow + 2 * l) = p0;
            if (l < 11) {
                uint_t p1 = (uint_t)f2bf(acc1.x) | ((uint_t)f2bf(acc1.y) << 16);
                *reinterpret_cast<uint_t*>(arow + 128 + 2 * l) = p1;
            }
            if (l < 5) *reinterpret_cast<uint_t*>(arow + 150 + 2 * l) = 0;
        }
    }
}

extern "C" void kernel_launch(void* const* d_in, const int* in_sizes, int n_in,
                              void* d_out, int out_size, void* d_ws, size_t ws_size,
                              hipStream_t stream) {
    const float* node_emb = (const float*)d_in[0];
    const float* w1 = (const float*)d_in[1];
    const float* root1 = (const float*)d_in[2];
    const float* b1 = (const float*)d_in[3];
    const float* w2 = (const float*)d_in[4];
    const float* root2 = (const float*)d_in[5];
    const float* b2 = (const float*)d_in[6];
    const int* edge_index = (const int*)d_in[7];
    const int* edge_type = (const int*)d_in[8];
    int N_ = in_sizes[0] / H;
    int E_ = in_sizes[8];
    float* out = (float*)d_out;

    const int Ncells = N_ * RNUM;
    const int wbtot = RNUM * BNUM * 2 * 16 * 32;

    int* ws = (int*)d_ws;
    size_t off = 0;
    int* cnt      = ws + off; off += Ncells;
    int* relhist2 = ws + off; off += 64;
    int* relfill2 = ws + off; off += 64;
    size_t zero_units = off;
    int* relbase2 = ws + off; off += 64;
    int* tprefix  = ws + off; off += 64;
    int* blkN     = ws + off; off += 64;
    int* blkD     = ws + off; off += 64;
    int* blkBN    = ws + off; off += 64;
    int* blkBD    = ws + off; off += 64;
    int* dstbase  = ws + off; off += N_ + 2;
    int* segoff   = ws + off; off += Ncells;
    int* segidx   = ws + off; off += Ncells;
    int* ssrc2    = ws + off; off += E_;
    off = (off + 3) & ~(size_t)3;
    int4* rec     = (int4*)(ws + off); off += (size_t)4 * Ncells;
    ushort_t* wbf1 = (ushort_t*)(ws + off); off += wbtot / 2;
    ushort_t* wbf2 = (ushort_t*)(ws + off); off += wbtot / 2;
    ushort_t* Bbf1 = (ushort_t*)(ws + off); off += 12800;
    ushort_t* Bbf2 = (ushort_t*)(ws + off); off += 12800;
    ushort_t* xbf  = (ushort_t*)(ws + off); off += (size_t)N_ * 160 / 2;  // node_emb bf16
    ushort_t* Abf  = (ushort_t*)(ws + off); off += (size_t)N_ * 160 / 2;  // layer-1 act bf16
    float* rootbuf = (float*)(ws + off); off += (size_t)N_ * H;
    __half* tseg  = (__half*)(ws + off);
    size_t tsegOffB = off * 4;

    size_t availB = (ws_size > tsegOffB) ? (ws_size - tsegOffB) : 0;
    long long dps_ll = (long long)(availB / ((size_t)RNUM * H * 2));
    int dps = (dps_ll > N_) ? N_ : (int)dps_ll;
    if (dps < 1) dps = 1;
    int nstripe = (N_ + dps - 1) / dps;

    hipMemsetAsync(cnt, 0, zero_units * 4, stream);

    k_count<<<512, 256, 0, stream>>>(edge_index, edge_type, E_, cnt);
    int nscan = (N_ + SCAN_SPAN - 1) / SCAN_SPAN;
    k_scanA<<<nscan, SCAN_BLOCK, 0, stream>>>(cnt, N_, blkN, blkD);
    k_scanB<<<1, 64, 0, stream>>>(blkN, blkD, blkBN, blkBD, nscan);
    k_scanC<<<nscan, SCAN_BLOCK, 0, stream>>>(cnt, N_, blkBN, blkBD, dstbase, segoff,
                                              segidx, relhist2);
    k_relbase<<<1, 64, 0, stream>>>(relhist2, relbase2, tprefix);
    k_scatter2<<<(E_ + 255) / 256, 256, 0, stream>>>(edge_index, edge_type, E_, segoff, ssrc2);
    k_relassign<<<64, 256, 0, stream>>>(cnt, segoff, segidx, Ncells, relbase2, relfill2, rec);
    k_prepw<<<(2 * wbtot + 255) / 256, 256, 0, stream>>>(w1, w2, wbf1, wbf2);
    k_convB<<<(2 * 160 * 160 + 255) / 256, 256, 0, stream>>>(root1, root2, Bbf1, Bbf2);
    k_convA<<<(N_ * 160 + 255) / 256, 256, 0, stream>>>(node_emb, xbf, N_);

    const int SEG_GRID = 1792;   // 7 LDS-resident blocks/CU * 256 CUs

    // ---- layer 1: gather from xbf (bf16) ----
    k_rootmm<<<dim3(40, 10), 256, 0, stream>>>(xbf, Bbf1, b1, rootbuf, N_);
    for (int st = 0; st < nstripe; ++st) {
        int s0 = st * dps;
        int s1 = s0 + dps; if (s1 > N_) s1 = N_;
        k_seg<<<SEG_GRID, 256, 0, stream>>>(rec, relbase2, tprefix, ssrc2, wbf1, xbf, tseg,
                                            dstbase + s0, dstbase + s1);
        k_aggadd<<<1280, 256, 0, stream>>>(tseg, dstbase, rootbuf, (float*)nullptr, Abf,
                                           1, s0, s1);
    }

    // ---- layer 2: gather from Abf (bf16) ----
    k_rootmm<<<dim3(40, 10), 256, 0, stream>>>(Abf, Bbf2, b2, out, N_);
    for (int st = 0; st < nstripe; ++st) {
        int s0 = st * dps;
        int s1 = s0 + dps; if (s1 > N_) s1 = N_;
        k_seg<<<SEG_GRID, 256, 0, stream>>>(rec, relbase2, tprefix, ssrc2, wbf2, Abf, tseg,
                                            dstbase + s0, dstbase + s1);
        k_aggadd<<<1280, 256, 0, stream>>>(tseg, dstbase, out, out, (ushort_t*)nullptr,
                                           0, s0, s1);
    }
}